// Round 10
// baseline (300.654 us; speedup 1.0000x reference)
//
#include <hip/hip_runtime.h>
#include <hip/hip_bf16.h>
#include <stdint.h>

#define T_LEN 1024
#define HIDN  1024
#define NH    16
#define DKV   64
#define KCONV 4
#define CG_IT 15
#define CC    32              // chunk length
#define NC    (T_LEN / CC)    // 32 chunks
#define PAD   68              // padded row stride (fp32 LDS tiles)

typedef __attribute__((ext_vector_type(8))) short          bf16x8;
typedef __attribute__((ext_vector_type(8))) unsigned short u16x8;
typedef __attribute__((ext_vector_type(4))) unsigned short u16x4;
typedef __attribute__((ext_vector_type(4))) float          f32x4;

__device__ __forceinline__ float softplusf(float x) {
    return x > 20.f ? x : log1pf(expf(x));
}
__device__ __forceinline__ unsigned short f2bf(float x) {
    __hip_bfloat16 b = __float2bfloat16(x);
    return *reinterpret_cast<unsigned short*>(&b);
}
__device__ __forceinline__ bf16x8 pack8(float4 a, float4 b) {
    union { bf16x8 v; unsigned short u[8]; } r;
    r.u[0] = f2bf(a.x); r.u[1] = f2bf(a.y); r.u[2] = f2bf(a.z); r.u[3] = f2bf(a.w);
    r.u[4] = f2bf(b.x); r.u[5] = f2bf(b.y); r.u[6] = f2bf(b.z); r.u[7] = f2bf(b.w);
    return r.v;
}

// ---------------------------------------------------------------------------
// Fused prep + proj_gb:
//   blocks [0,2048)      : cast hidden fp32->bf16
//   blocks [2048,3072)   : transpose+cast Wq/Wk/Wv/Wo
//   blocks [3072,3584)   : g/beta projections, one wave per row
// ---------------------------------------------------------------------------
__global__ __launch_bounds__(256) void prep_proj(const float* __restrict__ hidden,
                                                 const float* __restrict__ Wq,
                                                 const float* __restrict__ Wk,
                                                 const float* __restrict__ Wv,
                                                 const float* __restrict__ Wo,
                                                 const float* __restrict__ Wa,
                                                 const float* __restrict__ Wb,
                                                 const float* __restrict__ bb,
                                                 const float* __restrict__ A_log,
                                                 const float* __restrict__ dt_bias,
                                                 unsigned short* __restrict__ hidden_bf,
                                                 unsigned short* __restrict__ WqkvT,
                                                 unsigned short* __restrict__ WoT,
                                                 float* __restrict__ g_out,
                                                 float* __restrict__ beta_out)
{
    __shared__ unsigned short sT[64][68];
    int blk = blockIdx.x;
    int tid = threadIdx.x;
    if (blk < 2048) {
        int i = blk * 256 + tid;
        float4 v = *reinterpret_cast<const float4*>(hidden + (size_t)i * 4);
        u16x4 o;
        o.x = f2bf(v.x); o.y = f2bf(v.y); o.z = f2bf(v.z); o.w = f2bf(v.w);
        *reinterpret_cast<u16x4*>(hidden_bf + (size_t)i * 4) = o;
        return;
    }
    if (blk < 3072) {
        int r = blk - 2048;                 // 0..1023
        int m = r >> 8;                     // matrix 0..3
        int local = r & 255;
        int n0 = (local & 15) * 64, k0 = (local >> 4) * 64;
        const float* W = (m == 0) ? Wq : (m == 1) ? Wk : (m == 2) ? Wv : Wo;
        unsigned short* WT = (m < 3) ? (WqkvT + (size_t)m * HIDN * HIDN) : WoT;

        int rr = tid >> 4, cc4 = (tid & 15) * 4;
#pragma unroll
        for (int p = 0; p < 4; p++) {
            int rw = p * 16 + rr;
            float4 v = *reinterpret_cast<const float4*>(&W[(size_t)(k0 + rw) * HIDN + n0 + cc4]);
            sT[cc4 + 0][rw] = f2bf(v.x);
            sT[cc4 + 1][rw] = f2bf(v.y);
            sT[cc4 + 2][rw] = f2bf(v.z);
            sT[cc4 + 3][rw] = f2bf(v.w);
        }
        __syncthreads();
#pragma unroll
        for (int p = 0; p < 4; p++) {
            int rw = p * 16 + rr;
            u16x4 v = *reinterpret_cast<const u16x4*>(&sT[rw][cc4]);
            *reinterpret_cast<u16x4*>(&WT[(size_t)(n0 + rw) * HIDN + k0 + cc4]) = v;
        }
        return;
    }
    // ---- proj_gb ----
    int wvid = tid >> 6, lane = tid & 63;
    int row = (blk - 3072) * 4 + wvid;          // 0..2047
    const float* hr = hidden + (size_t)row * HIDN + 16 * lane;
    const float* war = Wa + (size_t)(16 * lane) * NH;
    const float* wbr = Wb + (size_t)(16 * lane) * NH;

    float da[16], db[16];
#pragma unroll
    for (int h = 0; h < 16; h++) { da[h] = 0.f; db[h] = 0.f; }

#pragma unroll
    for (int j = 0; j < 16; j += 4) {
        float4 xv = *reinterpret_cast<const float4*>(hr + j);
        float xs[4] = {xv.x, xv.y, xv.z, xv.w};
#pragma unroll
        for (int e = 0; e < 4; e++) {
            int i = j + e;
            float x = xs[e];
            const float4* wa4 = reinterpret_cast<const float4*>(war + i * NH);
            const float4* wb4 = reinterpret_cast<const float4*>(wbr + i * NH);
#pragma unroll
            for (int q = 0; q < 4; q++) {
                float4 wa = wa4[q], wb = wb4[q];
                da[q * 4 + 0] += x * wa.x; da[q * 4 + 1] += x * wa.y;
                da[q * 4 + 2] += x * wa.z; da[q * 4 + 3] += x * wa.w;
                db[q * 4 + 0] += x * wb.x; db[q * 4 + 1] += x * wb.y;
                db[q * 4 + 2] += x * wb.z; db[q * 4 + 3] += x * wb.w;
            }
        }
    }
#pragma unroll
    for (int m = 1; m < 64; m <<= 1) {
#pragma unroll
        for (int h = 0; h < 16; h++) {
            da[h] += __shfl_xor(da[h], m);
            db[h] += __shfl_xor(db[h], m);
        }
    }
    float dah = 0.f, dbh = 0.f;
#pragma unroll
    for (int h = 0; h < 16; h++) {
        bool sel = (lane == h);
        dah = sel ? da[h] : dah;
        dbh = sel ? db[h] : dbh;
    }
    if (lane < 16) {
        float sp = softplusf(dah + dt_bias[lane]);
        g_out[row * NH + lane]    = -expf(A_log[lane]) * sp;
        beta_out[row * NH + lane] = 1.f / (1.f + expf(-(dbh + bb[lane])));
    }
}

// ---------------------------------------------------------------------------
// bf16 MFMA GEMM (TN): C[M,N] = A[M,K] @ B^T, Bt is [N][K].  64x64 tile.
// (output projection)
// ---------------------------------------------------------------------------
__global__ __launch_bounds__(256) void gemm_bf16(const unsigned short* __restrict__ A,
                                                 const unsigned short* __restrict__ Bt,
                                                 float* __restrict__ C,
                                                 int M, int N, int K)
{
    __shared__ unsigned short sA[64][40];
    __shared__ unsigned short sB[64][40];
    const int tid = threadIdx.x;
    const int bm = blockIdx.y * 64, bn = blockIdx.x * 64;
    const int w = tid >> 6, lane = tid & 63;
    const int l16 = lane & 15, quad = lane >> 4;
    const int lrow = tid >> 2, lk = (tid & 3) * 8;

    f32x4 acc[4];
#pragma unroll
    for (int f = 0; f < 4; f++) acc[f] = (f32x4){0.f, 0.f, 0.f, 0.f};

    const size_t arow = (size_t)(bm + lrow) * K;
    const size_t brow = (size_t)(bn + lrow) * K;

    for (int k0 = 0; k0 < K; k0 += 32) {
        u16x8 av = *reinterpret_cast<const u16x8*>(A + arow + k0 + lk);
        u16x8 bv = *reinterpret_cast<const u16x8*>(Bt + brow + k0 + lk);
        *reinterpret_cast<u16x8*>(&sA[lrow][lk]) = av;
        *reinterpret_cast<u16x8*>(&sB[lrow][lk]) = bv;
        __syncthreads();

        bf16x8 aF = *reinterpret_cast<const bf16x8*>(&sA[w * 16 + l16][quad * 8]);
#pragma unroll
        for (int f = 0; f < 4; f++) {
            bf16x8 bF = *reinterpret_cast<const bf16x8*>(&sB[f * 16 + l16][quad * 8]);
            acc[f] = __builtin_amdgcn_mfma_f32_16x16x32_bf16(aF, bF, acc[f], 0, 0, 0);
        }
        __syncthreads();
    }

#pragma unroll
    for (int f = 0; f < 4; f++) {
#pragma unroll
        for (int i = 0; i < 4; i++) {
            int m = bm + w * 16 + quad * 4 + i;
            C[(size_t)m * N + bn + f * 16 + l16] = acc[f][i];
        }
    }
}

// ---------------------------------------------------------------------------
// Merged q/k/v GEMM, 128x128 tile, BK=32.
// ---------------------------------------------------------------------------
__global__ __launch_bounds__(256) void gemm_qkv128(const unsigned short* __restrict__ A,
                                                   const unsigned short* __restrict__ Bt,
                                                   float* __restrict__ C)
{
    const int K = 1024;
    __shared__ unsigned short sA[128][40];
    __shared__ unsigned short sB[128][40];
    const int tid = threadIdx.x;
    const int bm = blockIdx.y * 128;
    const int bn = blockIdx.x * 128;
    const int w = tid >> 6, lane = tid & 63;
    const int l16 = lane & 15, quad = lane >> 4;
    const int wm = (w >> 1) * 64, wn = (w & 1) * 64;
    const int lrow = tid >> 1, lk = (tid & 1) * 16;

    f32x4 acc[4][4];
#pragma unroll
    for (int i = 0; i < 4; i++)
#pragma unroll
        for (int f = 0; f < 4; f++) acc[i][f] = (f32x4){0.f, 0.f, 0.f, 0.f};

    const size_t arow = (size_t)(bm + lrow) * K + lk;
    const size_t brow = (size_t)(bn + lrow) * K + lk;

    for (int k0 = 0; k0 < K; k0 += 32) {
        u16x8 a0 = *reinterpret_cast<const u16x8*>(A + arow + k0);
        u16x8 a1 = *reinterpret_cast<const u16x8*>(A + arow + k0 + 8);
        u16x8 b0 = *reinterpret_cast<const u16x8*>(Bt + brow + k0);
        u16x8 b1 = *reinterpret_cast<const u16x8*>(Bt + brow + k0 + 8);
        *reinterpret_cast<u16x8*>(&sA[lrow][lk])     = a0;
        *reinterpret_cast<u16x8*>(&sA[lrow][lk + 8]) = a1;
        *reinterpret_cast<u16x8*>(&sB[lrow][lk])     = b0;
        *reinterpret_cast<u16x8*>(&sB[lrow][lk + 8]) = b1;
        __syncthreads();

        bf16x8 af[4], bf[4];
#pragma unroll
        for (int i = 0; i < 4; i++)
            af[i] = *reinterpret_cast<const bf16x8*>(&sA[wm + 16 * i + l16][8 * quad]);
#pragma unroll
        for (int f = 0; f < 4; f++)
            bf[f] = *reinterpret_cast<const bf16x8*>(&sB[wn + 16 * f + l16][8 * quad]);
#pragma unroll
        for (int i = 0; i < 4; i++)
#pragma unroll
            for (int f = 0; f < 4; f++)
                acc[i][f] = __builtin_amdgcn_mfma_f32_16x16x32_bf16(af[i], bf[f], acc[i][f], 0, 0, 0);
        __syncthreads();
    }

#pragma unroll
    for (int i = 0; i < 4; i++) {
#pragma unroll
        for (int f = 0; f < 4; f++) {
            int ncol = bn + wn + 16 * f + l16;
            int mat = ncol >> 10, nc = ncol & 1023;
            float* Cb = C + (size_t)mat * (2048u * 1024u) + nc;
            int mrow = bm + wm + 16 * i + 4 * quad;
#pragma unroll
            for (int reg = 0; reg < 4; reg++)
                Cb[(size_t)(mrow + reg) * 1024] = acc[i][f][reg];
        }
    }
}

// ---------------------------------------------------------------------------
// Inclusive cumsum of g over t per (b,h) via wave-scan (2 barriers).
// Also transposes beta to [b,h,t].
// ---------------------------------------------------------------------------
__global__ __launch_bounds__(256) void cumsum_g(const float* __restrict__ g_in,
                                                const float* __restrict__ beta_in,
                                                float* __restrict__ G_out,
                                                float* __restrict__ betaT)
{
    __shared__ float wtot[4];
    int bh = blockIdx.x;            // 0..31
    int b = bh >> 4, h = bh & 15;
    int tid = threadIdx.x;          // 0..255
    int wv = tid >> 6, lane = tid & 63;
    int t4 = tid * 4;
    size_t src = ((size_t)(b * T_LEN) + t4) * NH + h;
    float g0 = g_in[src], g1 = g_in[src + NH], g2 = g_in[src + 2 * NH], g3 = g_in[src + 3 * NH];
    float b0 = beta_in[src], b1 = beta_in[src + NH], b2 = beta_in[src + 2 * NH], b3 = beta_in[src + 3 * NH];
    float c1 = g0 + g1, c2 = c1 + g2, c3 = c2 + g3;
    float x = c3;
#pragma unroll
    for (int off = 1; off < 64; off <<= 1) {
        float y = __shfl_up(x, off);
        if (lane >= off) x += y;
    }
    float base = x - c3;            // exclusive prefix across lanes
    if (lane == 63) wtot[wv] = x;
    __syncthreads();
    float woff = 0.f;
#pragma unroll
    for (int q = 0; q < 4; q++) woff += (q < wv) ? wtot[q] : 0.f;
    base += woff;
    size_t dst = (size_t)bh * T_LEN + t4;
    G_out[dst]     = base + g0;
    G_out[dst + 1] = base + c1;
    G_out[dst + 2] = base + c2;
    G_out[dst + 3] = base + c3;
    betaT[dst] = b0; betaT[dst + 1] = b1; betaT[dst + 2] = b2; betaT[dst + 3] = b3;
}

// ---------------------------------------------------------------------------
// Fused causal depthwise conv (K=4) + silu + per-head l2norm for q AND k.
// ---------------------------------------------------------------------------
__global__ __launch_bounds__(256) void conv_silu_l2(const float* __restrict__ qpre,
                                                    const float* __restrict__ kpre,
                                                    const float* __restrict__ Wcq,
                                                    const float* __restrict__ Wck,
                                                    float* __restrict__ qbuf,
                                                    float* __restrict__ kbuf)
{
    int gidAll = blockIdx.x * 4 + (threadIdx.x >> 6);
    int which = gidAll >> 15;                 // 0 = q, 1 = k
    int gid = gidAll & 32767;
    const float* pre = which ? kpre : qpre;
    const float* Wc  = which ? Wck : Wcq;
    float* out       = which ? kbuf : qbuf;
    int lane = threadIdx.x & 63;
    int h = gid & 15;
    int t = (gid >> 4) & (T_LEN - 1);
    int b = gid >> 14;
    int c = h * DKV + lane;
    float acc = 0.f;
#pragma unroll
    for (int i = 0; i < KCONV; i++) {
        int ts = t - (KCONV - 1) + i;
        if (ts >= 0)
            acc += pre[((size_t)(b * T_LEN) + ts) * HIDN + c] * Wc[c * KCONV + i];
    }
    float y = acc / (1.f + expf(-acc));
    float ss = y * y;
#pragma unroll
    for (int m = 1; m < 64; m <<= 1) ss += __shfl_xor(ss, m);
    out[((size_t)(b * T_LEN) + t) * HIDN + c] = y * rsqrtf(ss + 1e-6f);
}

// ---------------------------------------------------------------------------
// Stage 1: per-chunk local contributions (fully parallel).
// ---------------------------------------------------------------------------
__global__ __launch_bounds__(256) void chunk_local(const float* __restrict__ kbuf,
                                                   const float* __restrict__ vbuf,
                                                   const float* __restrict__ G,
                                                   const float* __restrict__ betaT,
                                                   float* __restrict__ Akk,
                                                   float* __restrict__ AkvT)
{
    __shared__ float sK[CC][PAD];
    __shared__ float sV[CC][PAD];
    __shared__ float sW[CC];
    int bid = blockIdx.x;                 // 2048
    int half = bid & 1;
    int cidx = bid >> 1;
    int chunk = cidx & (NC - 1), bh = cidx >> 5;
    int b = bh >> 4, h = bh & 15;
    int tid = threadIdx.x;
    int i = half * 32 + (tid >> 3);
    int j0 = (tid & 7) * 8;
    int ls = tid >> 3, ld = (tid & 7) * 8;
    int t0 = chunk * CC;

    {
        size_t ga = (((size_t)(b * T_LEN) + t0 + ls) * NH + h) * 64 + ld;
        *reinterpret_cast<float4*>(&sK[ls][ld])     = *reinterpret_cast<const float4*>(&kbuf[ga]);
        *reinterpret_cast<float4*>(&sK[ls][ld + 4]) = *reinterpret_cast<const float4*>(&kbuf[ga + 4]);
        *reinterpret_cast<float4*>(&sV[ls][ld])     = *reinterpret_cast<const float4*>(&vbuf[ga]);
        *reinterpret_cast<float4*>(&sV[ls][ld + 4]) = *reinterpret_cast<const float4*>(&vbuf[ga + 4]);
        if (tid < CC) {
            float gv = G[(size_t)bh * T_LEN + t0 + tid];
            float bv = betaT[(size_t)bh * T_LEN + t0 + tid];
            float gend = __shfl(gv, 31);
            sW[tid] = expf(gend - gv) * bv;
        }
    }
    __syncthreads();

    float akk[8], akv[8];
#pragma unroll
    for (int j = 0; j < 8; j++) { akk[j] = 0.f; akv[j] = 0.f; }
#pragma unroll 4
    for (int s = 0; s < CC; s++) {
        float wk = sW[s] * sK[s][i];
        float wv = sW[s] * sV[s][i];
        float4 ka = *reinterpret_cast<const float4*>(&sK[s][j0]);
        float4 kb = *reinterpret_cast<const float4*>(&sK[s][j0 + 4]);
        akk[0] += wk * ka.x; akk[1] += wk * ka.y; akk[2] += wk * ka.z; akk[3] += wk * ka.w;
        akk[4] += wk * kb.x; akk[5] += wk * kb.y; akk[6] += wk * kb.z; akk[7] += wk * kb.w;
        akv[0] += wv * ka.x; akv[1] += wv * ka.y; akv[2] += wv * ka.z; akv[3] += wv * ka.w;
        akv[4] += wv * kb.x; akv[5] += wv * kb.y; akv[6] += wv * kb.z; akv[7] += wv * kb.w;
    }
    size_t ob = ((size_t)cidx * 64 + i) * 64 + j0;
    *reinterpret_cast<float4*>(&Akk[ob])      = make_float4(akk[0], akk[1], akk[2], akk[3]);
    *reinterpret_cast<float4*>(&Akk[ob + 4])  = make_float4(akk[4], akk[5], akk[6], akk[7]);
    *reinterpret_cast<float4*>(&AkvT[ob])     = make_float4(akv[0], akv[1], akv[2], akv[3]);
    *reinterpret_cast<float4*>(&AkvT[ob + 4]) = make_float4(akv[4], akv[5], akv[6], akv[7]);
}

// ---------------------------------------------------------------------------
// Stage 2: element-parallel prefix over chunks, 4-batched loads.
// Hkk emitted as BF16 into Hkk_bf (fits qpre exactly, 8 MB);
// HkvT converted fp32 in-place (R8 scheme -- no aliasing hazard).
// ---------------------------------------------------------------------------
__global__ __launch_bounds__(256) void chunk_prefix(const float* __restrict__ Akk,
                                                    float* __restrict__ HkvT,
                                                    const float* __restrict__ G,
                                                    unsigned short* __restrict__ Hkk_bf)
{
    __shared__ float sDec[NC];
    int blk = blockIdx.x;                 // 256
    int bh = blk >> 3, sub = blk & 7;
    int tid = threadIdx.x;
    if (tid < NC)
        sDec[tid] = (tid > 0)
            ? expf(G[(size_t)bh * T_LEN + tid * CC + CC - 1] - G[(size_t)bh * T_LEN + tid * CC - 1])
            : 1.f;
    __syncthreads();
    int flat = sub * 256 + tid;           // 0..2047
    int mat = flat >> 10, e4 = flat & 1023;
    float4 state = make_float4(0.f, 0.f, 0.f, 0.f);
    if (mat == 0) {
        const float* src = Akk + (size_t)bh * NC * 4096 + (size_t)e4 * 4;
        unsigned short* dst = Hkk_bf + (size_t)bh * NC * 4096 + (size_t)e4 * 4;
#pragma unroll 1
        for (int c0 = 0; c0 < NC; c0 += 4) {
            float4 av[4];
#pragma unroll
            for (int e = 0; e < 4; e++)
                av[e] = *reinterpret_cast<const float4*>(src + (size_t)(c0 + e) * 4096);
#pragma unroll
            for (int e = 0; e < 4; e++) {
                u16x4 o;
                o.x = f2bf(state.x); o.y = f2bf(state.y); o.z = f2bf(state.z); o.w = f2bf(state.w);
                *reinterpret_cast<u16x4*>(dst + (size_t)(c0 + e) * 4096) = o;
                float d = sDec[c0 + e];
                state.x = d * state.x + av[e].x;
                state.y = d * state.y + av[e].y;
                state.z = d * state.z + av[e].z;
                state.w = d * state.w + av[e].w;
            }
        }
    } else {
        float* base = HkvT + (size_t)bh * NC * 4096 + (size_t)e4 * 4;
#pragma unroll 1
        for (int c0 = 0; c0 < NC; c0 += 4) {
            float4 av[4];
#pragma unroll
            for (int e = 0; e < 4; e++)
                av[e] = *reinterpret_cast<const float4*>(base + (size_t)(c0 + e) * 4096);
#pragma unroll
            for (int e = 0; e < 4; e++) {
                *reinterpret_cast<float4*>(base + (size_t)(c0 + e) * 4096) = state;
                float d = sDec[c0 + e];
                state.x = d * state.x + av[e].x;
                state.y = d * state.y + av[e].y;
                state.z = d * state.z + av[e].z;
                state.w = d * state.w + av[e].w;
            }
        }
    }
}

// ---------------------------------------------------------------------------
// MFMA scan: ONE WAVE per (bh, chunk, half16) -> 2048 waves, 512 blocks.
// ---------------------------------------------------------------------------
__global__ __launch_bounds__(256, 2) void scan_mfma(
    const float* __restrict__ qbuf, const float* __restrict__ kbuf,
    const float* __restrict__ vbuf, const float* __restrict__ G,
    const float* __restrict__ betaT, const unsigned short* __restrict__ Hkk_bf,
    const float* __restrict__ HkvT0, const float* __restrict__ lambda_p,
    const float* __restrict__ norm_w, unsigned short* __restrict__ obf)
{
    __shared__ __align__(16) unsigned short sP[4][16][72];
    __shared__ __align__(16) unsigned short sM[4][16][40];

    const int tid = threadIdx.x;
    const int wv = tid >> 6, lane = tid & 63;
    const int quad = lane >> 4, l16 = lane & 15;
    const int W = blockIdx.x * 4 + wv;          // 0..2047
    const int half = W & 1;
    const int cidx = W >> 1;                    // 0..1023
    const int bh = cidx >> 5, chunk = cidx & 31;
    const int b = bh >> 4, h = bh & 15;
    const int t0 = chunk * CC;
    const int rbofs = 16 * half + 4 * quad;     // +reg -> local t-row
    unsigned short (*sPw)[72] = sP[wv];
    unsigned short (*sMw)[40] = sM[wv];

    const size_t rbase = ((size_t)(b * T_LEN + t0) * NH + h) * 64;
    const float* Gb = G + (size_t)bh * T_LEN + t0;
    const float* Bb = betaT + (size_t)bh * T_LEN + t0;
    const float Gprev = (chunk > 0) ? Gb[-1] : 0.f;

    float Gt[4], et[4];
#pragma unroll
    for (int reg = 0; reg < 4; reg++) {
        float g = Gb[rbofs + reg];
        Gt[reg] = g;
        et[reg] = expf(g - Gprev);
    }
    float Co[2][4];
#pragma unroll
    for (int sn = 0; sn < 2; sn++) {
        int s = 16 * sn + l16;
        float Gs = Gb[s], bts = Bb[s];
#pragma unroll
        for (int reg = 0; reg < 4; reg++) {
            int t = rbofs + reg;
            Co[sn][reg] = (s <= t) ? expf(Gt[reg] - Gs) * bts : 0.f;
        }
    }
    float lam[4], nw[4];
#pragma unroll
    for (int f = 0; f < 4; f++) {
        lam[f] = softplusf(lambda_p[h * 64 + 16 * f + l16]) + 0.25f;
        nw[f]  = norm_w[16 * f + l16];
    }

    bf16x8 Kb[2][2];
#pragma unroll
    for (int sn = 0; sn < 2; sn++) {
        const float* kr = kbuf + rbase + (size_t)(16 * sn + l16) * 1024;
#pragma unroll
        for (int ks = 0; ks < 2; ks++) {
            float4 a = *reinterpret_cast<const float4*>(kr + 8 * quad + 32 * ks);
            float4 c = *reinterpret_cast<const float4*>(kr + 8 * quad + 32 * ks + 4);
            Kb[sn][ks] = pack8(a, c);
        }
    }
    bf16x8 KTb[4];
#pragma unroll
    for (int f = 0; f < 4; f++) {
        union { bf16x8 v; unsigned short u[8]; } r;
#pragma unroll
        for (int j = 0; j < 8; j++)
            r.u[j] = f2bf(kbuf[rbase + (size_t)(8 * quad + j) * 1024 + 16 * f + l16]);
        KTb[f] = r.v;
    }
    const size_t hbase = ((size_t)(bh * NC) + chunk) * 4096;
    bf16x8 Hb[4][2];
#pragma unroll
    for (int f = 0; f < 4; f++) {
        const unsigned short* hr = Hkk_bf + hbase + (size_t)(16 * f + l16) * 64;
#pragma unroll
        for (int ks = 0; ks < 2; ks++)
            Hb[f][ks] = *reinterpret_cast<const bf16x8*>(hr + 8 * quad + 32 * ks);
    }

    f32x4 X[4], R[4], P[4];
    float rs8[4];
#pragma unroll
    for (int reg = 0; reg < 4; reg++) rs8[reg] = 0.f;
#pragma unroll
    for (int f = 0; f < 4; f++) {
#pragma unroll
        for (int reg = 0; reg < 4; reg++) {
            float q = qbuf[rbase + (size_t)(rbofs + reg) * 1024 + 16 * f + l16];
            P[f][reg] = q; R[f][reg] = q; X[f][reg] = 0.f;
            rs8[reg] += q * q;
        }
    }
#pragma unroll
    for (int reg = 0; reg < 4; reg++) {
        float v = rs8[reg];
        v += __shfl_xor(v, 1); v += __shfl_xor(v, 2);
        v += __shfl_xor(v, 4); v += __shfl_xor(v, 8);
        rs8[reg] = v;
    }

    const f32x4 zero4 = {0.f, 0.f, 0.f, 0.f};

#pragma unroll 1
    for (int it = 0; it < CG_IT; it++) {
#pragma unroll
        for (int reg = 0; reg < 4; reg++)
#pragma unroll
            for (int f = 0; f < 4; f++)
                sPw[4 * quad + reg][16 * f + l16] = f2bf(P[f][reg]);
        __threadfence_block();
        bf16x8 Pa[2];
#pragma unroll
        for (int ks = 0; ks < 2; ks++)
            Pa[ks] = *reinterpret_cast<const bf16x8*>(&sPw[l16][8 * quad + 32 * ks]);
        f32x4 D[2];
#pragma unroll
        for (int sn = 0; sn < 2; sn++) {
            f32x4 d = __builtin_amdgcn_mfma_f32_16x16x32_bf16(Pa[0], Kb[sn][0], zero4, 0, 0, 0);
            D[sn] = __builtin_amdgcn_mfma_f32_16x16x32_bf16(Pa[1], Kb[sn][1], d, 0, 0, 0);
        }
#pragma unroll
        for (int sn = 0; sn < 2; sn++)
#pragma unroll
            for (int reg = 0; reg < 4; reg++)
                sMw[4 * quad + reg][16 * sn + l16] = f2bf(Co[sn][reg] * D[sn][reg]);
        __threadfence_block();
        bf16x8 Ma = *reinterpret_cast<const bf16x8*>(&sMw[l16][8 * quad]);
        f32x4 AP[4], A2[4];
#pragma unroll
        for (int f = 0; f < 4; f++) {
            AP[f] = __builtin_amdgcn_mfma_f32_16x16x32_bf16(Ma, KTb[f], zero4, 0, 0, 0);
            f32x4 a = __builtin_amdgcn_mfma_f32_16x16x32_bf16(Pa[0], Hb[f][0], zero4, 0, 0, 0);
            A2[f] = __builtin_amdgcn_mfma_f32_16x16x32_bf16(Pa[1], Hb[f][1], a, 0, 0, 0);
        }
#pragma unroll
        for (int f = 0; f < 4; f++)
#pragma unroll
            for (int reg = 0; reg < 4; reg++)
                AP[f][reg] = lam[f] * P[f][reg] + AP[f][reg] + et[reg] * A2[f][reg];
        float alpha[4], rsn[4];
#pragma unroll
        for (int reg = 0; reg < 4; reg++) {
            float s = 0.f;
#pragma unroll
            for (int f = 0; f < 4; f++) s += P[f][reg] * AP[f][reg];
            s += __shfl_xor(s, 1); s += __shfl_xor(s, 2);
            s += __shfl_xor(s, 4); s += __shfl_xor(s, 8);
            alpha[reg] = rs8[reg] / (s + 1e-12f);
            rsn[reg] = 0.f;
        }
#pragma unroll
        for (int f = 0; f < 4; f++)
#pragma unroll
            for (int reg = 0; reg < 4; reg++) {
                X[f][reg] += alpha[reg] * P[f][reg];
                float rv = R[f][reg] - alpha[reg] * AP[f][reg];
                R[f][reg] = rv;
                rsn[reg] += rv * rv;
            }
#pragma unroll
        for (int reg = 0; reg < 4; reg++) {
            float v = rsn[reg];
            v += __shfl_xor(v, 1); v += __shfl_xor(v, 2);
            v += __shfl_xor(v, 4); v += __shfl_xor(v, 8);
            float btac = v / (rs8[reg] + 1e-12f);
            rs8[reg] = v;
#pragma unroll
            for (int f = 0; f < 4; f++)
                P[f][reg] = R[f][reg] + btac * P[f][reg];
        }
    }

    // ---- output phase ----
#pragma unroll
    for (int reg = 0; reg < 4; reg++)
#pragma unroll
        for (int f = 0; f < 4; f++)
            sPw[4 * quad + reg][16 * f + l16] = f2bf(X[f][reg]);
    __threadfence_block();
    bf16x8 Xa[2];
#pragma unroll
    for (int ks = 0; ks < 2; ks++)
        Xa[ks] = *reinterpret_cast<const bf16x8*>(&sPw[l16][8 * quad + 32 * ks]);
    f32x4 Do[2];
#pragma unroll
    for (int sn = 0; sn < 2; sn++) {
        f32x4 d = __builtin_amdgcn_mfma_f32_16x16x32_bf16(Xa[0], Kb[sn][0], zero4, 0, 0, 0);
        Do[sn] = __builtin_amdgcn_mfma_f32_16x16x32_bf16(Xa[1], Kb[sn][1], d, 0, 0, 0);
    }
#pragma unroll
    for (int sn = 0; sn < 2; sn++)
#pragma unroll
        for (int reg = 0; reg < 4; reg++)
            sMw[4 * quad + reg][16 * sn + l16] = f2bf(Co[sn][reg] * Do[sn][reg]);
    __threadfence_block();
    bf16x8 Mo = *reinterpret_cast<const bf16x8*>(&sMw[l16][8 * quad]);
    bf16x8 Vb[4];
#pragma unroll
    for (int f = 0; f < 4; f++) {
        union { bf16x8 v; unsigned short u[8]; } r;
#pragma unroll
        for (int j = 0; j < 8; j++)
            r.u[j] = f2bf(vbuf[rbase + (size_t)(8 * quad + j) * 1024 + 16 * f + l16]);
        Vb[f] = r.v;
    }
    bf16x8 Hvb[4][2];
#pragma unroll
    for (int f = 0; f < 4; f++) {
        const float* hr = HkvT0 + hbase + (size_t)(16 * f + l16) * 64;
#pragma unroll
        for (int ks = 0; ks < 2; ks++) {
            float4 a = *reinterpret_cast<const float4*>(hr + 8 * quad + 32 * ks);
            float4 c = *reinterpret_cast<const float4*>(hr + 8 * quad + 32 * ks + 4);
            Hvb[f][ks] = pack8(a, c);
        }
    }
    f32x4 O[4];
#pragma unroll
    for (int f = 0; f < 4; f++) {
        f32x4 o1 = __builtin_amdgcn_mfma_f32_16x16x32_bf16(Mo, Vb[f], zero4, 0, 0, 0);
        f32x4 o2 = __builtin_amdgcn_mfma_f32_16x16x32_bf16(Xa[0], Hvb[f][0], zero4, 0, 0, 0);
        o2 = __builtin_amdgcn_mfma_f32_16x16x32_bf16(Xa[1], Hvb[f][1], o2, 0, 0, 0);
#pragma unroll
        for (int reg = 0; reg < 4; reg++)
            O[f][reg] = o1[reg] + et[reg] * o2[reg];
    }
#pragma unroll
    for (int reg = 0; reg < 4; reg++) {
        float s = 0.f;
#pragma unroll
        for (int f = 0; f < 4; f++) s += O[f][reg] * O[f][reg];
        s += __shfl_xor(s, 1); s += __shfl_xor(s, 2);
        s += __shfl_xor(s, 4); s += __shfl_xor(s, 8);
        float scale = rsqrtf(s * (1.f / 64.f) + 1e-5f);
        size_t orow = rbase + (size_t)(rbofs + reg) * 1024;
#pragma unroll
        for (int f = 0; f < 4; f++)
            obf[orow + 16 * f + l16] = f2bf(O[f][reg] * scale * nw[f]);
    }
}

// ---------------------------------------------------------------------------
extern "C" void kernel_launch(void* const* d_in, const int* in_sizes, int n_in,
                              void* d_out, int out_size, void* d_ws, size_t ws_size,
                              hipStream_t stream)
{
    const float* hidden   = (const float*)d_in[0];
    const float* Wq       = (const float*)d_in[1];
    const float* Wk       = (const float*)d_in[2];
    const float* Wv       = (const float*)d_in[3];
    const float* Wa       = (const float*)d_in[4];
    const float* Wb       = (const float*)d_in[5];
    const float* bb       = (const float*)d_in[6];
    const float* A_log    = (const float*)d_in[7];
    const float* dt_bias  = (const float*)d_in[8];
    const float* lambda_p = (const float*)d_in[9];
    const float* Wconv_q  = (const float*)d_in[10];
    const float* Wconv_k  = (const float*)d_in[11];
    const float* norm_w   = (const float*)d_in[12];
    const float* Wo       = (const float*)d_in[13];
    float* out = (float*)d_out;

    float* ws = (float*)d_ws;
    const size_t SZ_BIG = (size_t)2 * T_LEN * HIDN;   // 2M floats (8 MB)
    float* qpre = ws;
    float* kpre = qpre + SZ_BIG;
    float* vbuf = kpre + SZ_BIG;
    float* qbuf = vbuf + SZ_BIG;
    float* kbuf = qbuf + SZ_BIG;
    float* gbuf = kbuf + SZ_BIG;
    float* bbuf = gbuf + 32768;
    float* Gbuf = bbuf + 32768;
    float* btT  = Gbuf + 32768;
    float* Akk  = btT + 32768;                        // 4M floats (16 MB)
    float* AkvT = Akk + (size_t)32 * NC * 4096;       // 4M floats -> HkvT in-place
    unsigned short* WoT = (unsigned short*)(AkvT + (size_t)32 * NC * 4096);

    unsigned short* hidden_bf = (unsigned short*)AkvT;    // dead before chunk_local
    unsigned short* WqkvT = (unsigned short*)Akk;         // dead before chunk_local
    unsigned short* obuf_bf = (unsigned short*)kpre;      // kpre dead after conv
    unsigned short* Hkk_bf = (unsigned short*)qpre;       // qpre dead after conv (8 MB exact fit)

    const int M = 2 * T_LEN;                          // 2048

    prep_proj<<<3584, 256, 0, stream>>>(hidden, Wq, Wk, Wv, Wo, Wa, Wb, bb, A_log,
                                        dt_bias, hidden_bf, WqkvT, WoT, gbuf, bbuf);

    dim3 gq(3 * HIDN / 128, M / 128);                 // (24, 16)
    gemm_qkv128<<<gq, 256, 0, stream>>>(hidden_bf, WqkvT, qpre);
    cumsum_g<<<32, 256, 0, stream>>>(gbuf, bbuf, Gbuf, btT);
    conv_silu_l2<<<2 * M * NH / 4, 256, 0, stream>>>(qpre, kpre, Wconv_q, Wconv_k,
                                                     qbuf, kbuf);
    chunk_local<<<2048, 256, 0, stream>>>(kbuf, vbuf, Gbuf, btT, Akk, AkvT);
    chunk_prefix<<<256, 256, 0, stream>>>(Akk, AkvT, Gbuf, Hkk_bf);
    scan_mfma<<<512, 256, 0, stream>>>(qbuf, kbuf, vbuf, Gbuf, btT, Hkk_bf, AkvT,
                                       lambda_p, norm_w, obuf_bf);
    dim3 gg(HIDN / 64, M / 64);
    gemm_bf16<<<gg, 256, 0, stream>>>(obuf_bf, WoT, out, M, HIDN, HIDN);
}

// Round 11
// 251.000 us; speedup vs baseline: 1.1978x; 1.1978x over previous
//
#include <hip/hip_runtime.h>
#include <hip/hip_bf16.h>
#include <stdint.h>

#define T_LEN 1024
#define HIDN  1024
#define NH    16
#define DKV   64
#define KCONV 4
#define CG_IT 15
#define CC    32              // chunk length
#define NC    (T_LEN / CC)    // 32 chunks
#define PAD   68              // padded row stride (fp32 LDS tiles)

typedef __attribute__((ext_vector_type(8))) short          bf16x8;
typedef __attribute__((ext_vector_type(8))) unsigned short u16x8;
typedef __attribute__((ext_vector_type(4))) unsigned short u16x4;
typedef __attribute__((ext_vector_type(4))) float          f32x4;

__device__ __forceinline__ float softplusf(float x) {
    return x > 20.f ? x : log1pf(expf(x));
}
__device__ __forceinline__ unsigned short f2bf(float x) {
    __hip_bfloat16 b = __float2bfloat16(x);
    return *reinterpret_cast<unsigned short*>(&b);
}
__device__ __forceinline__ bf16x8 pack8(float4 a, float4 b) {
    union { bf16x8 v; unsigned short u[8]; } r;
    r.u[0] = f2bf(a.x); r.u[1] = f2bf(a.y); r.u[2] = f2bf(a.z); r.u[3] = f2bf(a.w);
    r.u[4] = f2bf(b.x); r.u[5] = f2bf(b.y); r.u[6] = f2bf(b.z); r.u[7] = f2bf(b.w);
    return r.v;
}

// ---------------------------------------------------------------------------
// prep: blocks [0,2048) cast hidden fp32->bf16; blocks [2048,3072)
// transpose+cast the four weight matrices.
// ---------------------------------------------------------------------------
__global__ __launch_bounds__(256) void prep(const float* __restrict__ hidden,
                                            const float* __restrict__ Wq,
                                            const float* __restrict__ Wk,
                                            const float* __restrict__ Wv,
                                            const float* __restrict__ Wo,
                                            unsigned short* __restrict__ hidden_bf,
                                            unsigned short* __restrict__ WqkvT,
                                            unsigned short* __restrict__ WoT)
{
    __shared__ unsigned short sT[64][68];
    int blk = blockIdx.x;
    int tid = threadIdx.x;
    if (blk < 2048) {
        int i = blk * 256 + tid;
        float4 v = *reinterpret_cast<const float4*>(hidden + (size_t)i * 4);
        u16x4 o;
        o.x = f2bf(v.x); o.y = f2bf(v.y); o.z = f2bf(v.z); o.w = f2bf(v.w);
        *reinterpret_cast<u16x4*>(hidden_bf + (size_t)i * 4) = o;
        return;
    }
    int r = blk - 2048;                 // 0..1023
    int m = r >> 8;                     // matrix 0..3
    int local = r & 255;
    int n0 = (local & 15) * 64, k0 = (local >> 4) * 64;
    const float* W = (m == 0) ? Wq : (m == 1) ? Wk : (m == 2) ? Wv : Wo;
    unsigned short* WT = (m < 3) ? (WqkvT + (size_t)m * HIDN * HIDN) : WoT;

    int rr = tid >> 4, cc4 = (tid & 15) * 4;
#pragma unroll
    for (int p = 0; p < 4; p++) {
        int rw = p * 16 + rr;
        float4 v = *reinterpret_cast<const float4*>(&W[(size_t)(k0 + rw) * HIDN + n0 + cc4]);
        sT[cc4 + 0][rw] = f2bf(v.x);
        sT[cc4 + 1][rw] = f2bf(v.y);
        sT[cc4 + 2][rw] = f2bf(v.z);
        sT[cc4 + 3][rw] = f2bf(v.w);
    }
    __syncthreads();
#pragma unroll
    for (int p = 0; p < 4; p++) {
        int rw = p * 16 + rr;
        u16x4 v = *reinterpret_cast<const u16x4*>(&sT[rw][cc4]);
        *reinterpret_cast<u16x4*>(&WT[(size_t)(n0 + rw) * HIDN + k0 + cc4]) = v;
    }
}

// ---------------------------------------------------------------------------
// g / beta projections: one wave per row, COALESCED weight access.
// Lane l handles hidden elements i = j*64 + l (j = 0..15).
// ---------------------------------------------------------------------------
__global__ __launch_bounds__(256) void proj_gb(const float* __restrict__ hidden,
                                               const float* __restrict__ Wa,
                                               const float* __restrict__ Wb,
                                               const float* __restrict__ bb,
                                               const float* __restrict__ A_log,
                                               const float* __restrict__ dt_bias,
                                               float* __restrict__ g_out,
                                               float* __restrict__ beta_out)
{
    int wvid = threadIdx.x >> 6, lane = threadIdx.x & 63;
    int row = blockIdx.x * 4 + wvid;            // 0..2047
    const float* hr = hidden + (size_t)row * HIDN;

    float da[16], db[16];
#pragma unroll
    for (int h = 0; h < 16; h++) { da[h] = 0.f; db[h] = 0.f; }

#pragma unroll 4
    for (int j = 0; j < 16; j++) {
        int i = j * 64 + lane;
        float x = hr[i];
        const float4* wa4 = reinterpret_cast<const float4*>(Wa + (size_t)i * NH);
        const float4* wb4 = reinterpret_cast<const float4*>(Wb + (size_t)i * NH);
#pragma unroll
        for (int q = 0; q < 4; q++) {
            float4 wa = wa4[q], wb = wb4[q];
            da[q * 4 + 0] += x * wa.x; da[q * 4 + 1] += x * wa.y;
            da[q * 4 + 2] += x * wa.z; da[q * 4 + 3] += x * wa.w;
            db[q * 4 + 0] += x * wb.x; db[q * 4 + 1] += x * wb.y;
            db[q * 4 + 2] += x * wb.z; db[q * 4 + 3] += x * wb.w;
        }
    }
#pragma unroll
    for (int m = 1; m < 64; m <<= 1) {
#pragma unroll
        for (int h = 0; h < 16; h++) {
            da[h] += __shfl_xor(da[h], m);
            db[h] += __shfl_xor(db[h], m);
        }
    }
    float dah = 0.f, dbh = 0.f;
#pragma unroll
    for (int h = 0; h < 16; h++) {
        bool sel = (lane == h);
        dah = sel ? da[h] : dah;
        dbh = sel ? db[h] : dbh;
    }
    if (lane < 16) {
        float sp = softplusf(dah + dt_bias[lane]);
        g_out[row * NH + lane]    = -expf(A_log[lane]) * sp;
        beta_out[row * NH + lane] = 1.f / (1.f + expf(-(dbh + bb[lane])));
    }
}

// ---------------------------------------------------------------------------
// bf16 MFMA GEMM (TN): C[M,N] = A[M,K] @ B^T, Bt is [N][K].  64x64 tile.
// (output projection)
// ---------------------------------------------------------------------------
__global__ __launch_bounds__(256) void gemm_bf16(const unsigned short* __restrict__ A,
                                                 const unsigned short* __restrict__ Bt,
                                                 float* __restrict__ C,
                                                 int M, int N, int K)
{
    __shared__ unsigned short sA[64][40];
    __shared__ unsigned short sB[64][40];
    const int tid = threadIdx.x;
    const int bm = blockIdx.y * 64, bn = blockIdx.x * 64;
    const int w = tid >> 6, lane = tid & 63;
    const int l16 = lane & 15, quad = lane >> 4;
    const int lrow = tid >> 2, lk = (tid & 3) * 8;

    f32x4 acc[4];
#pragma unroll
    for (int f = 0; f < 4; f++) acc[f] = (f32x4){0.f, 0.f, 0.f, 0.f};

    const size_t arow = (size_t)(bm + lrow) * K;
    const size_t brow = (size_t)(bn + lrow) * K;

    for (int k0 = 0; k0 < K; k0 += 32) {
        u16x8 av = *reinterpret_cast<const u16x8*>(A + arow + k0 + lk);
        u16x8 bv = *reinterpret_cast<const u16x8*>(Bt + brow + k0 + lk);
        *reinterpret_cast<u16x8*>(&sA[lrow][lk]) = av;
        *reinterpret_cast<u16x8*>(&sB[lrow][lk]) = bv;
        __syncthreads();

        bf16x8 aF = *reinterpret_cast<const bf16x8*>(&sA[w * 16 + l16][quad * 8]);
#pragma unroll
        for (int f = 0; f < 4; f++) {
            bf16x8 bF = *reinterpret_cast<const bf16x8*>(&sB[f * 16 + l16][quad * 8]);
            acc[f] = __builtin_amdgcn_mfma_f32_16x16x32_bf16(aF, bF, acc[f], 0, 0, 0);
        }
        __syncthreads();
    }

#pragma unroll
    for (int f = 0; f < 4; f++) {
#pragma unroll
        for (int i = 0; i < 4; i++) {
            int m = bm + w * 16 + quad * 4 + i;
            C[(size_t)m * N + bn + f * 16 + l16] = acc[f][i];
        }
    }
}

// ---------------------------------------------------------------------------
// Merged q/k/v GEMM, 128x128 tile, BK=32.
// ---------------------------------------------------------------------------
__global__ __launch_bounds__(256) void gemm_qkv128(const unsigned short* __restrict__ A,
                                                   const unsigned short* __restrict__ Bt,
                                                   float* __restrict__ C)
{
    const int K = 1024;
    __shared__ unsigned short sA[128][40];
    __shared__ unsigned short sB[128][40];
    const int tid = threadIdx.x;
    const int bm = blockIdx.y * 128;
    const int bn = blockIdx.x * 128;
    const int w = tid >> 6, lane = tid & 63;
    const int l16 = lane & 15, quad = lane >> 4;
    const int wm = (w >> 1) * 64, wn = (w & 1) * 64;
    const int lrow = tid >> 1, lk = (tid & 1) * 16;

    f32x4 acc[4][4];
#pragma unroll
    for (int i = 0; i < 4; i++)
#pragma unroll
        for (int f = 0; f < 4; f++) acc[i][f] = (f32x4){0.f, 0.f, 0.f, 0.f};

    const size_t arow = (size_t)(bm + lrow) * K + lk;
    const size_t brow = (size_t)(bn + lrow) * K + lk;

    for (int k0 = 0; k0 < K; k0 += 32) {
        u16x8 a0 = *reinterpret_cast<const u16x8*>(A + arow + k0);
        u16x8 a1 = *reinterpret_cast<const u16x8*>(A + arow + k0 + 8);
        u16x8 b0 = *reinterpret_cast<const u16x8*>(Bt + brow + k0);
        u16x8 b1 = *reinterpret_cast<const u16x8*>(Bt + brow + k0 + 8);
        *reinterpret_cast<u16x8*>(&sA[lrow][lk])     = a0;
        *reinterpret_cast<u16x8*>(&sA[lrow][lk + 8]) = a1;
        *reinterpret_cast<u16x8*>(&sB[lrow][lk])     = b0;
        *reinterpret_cast<u16x8*>(&sB[lrow][lk + 8]) = b1;
        __syncthreads();

        bf16x8 af[4], bf[4];
#pragma unroll
        for (int i = 0; i < 4; i++)
            af[i] = *reinterpret_cast<const bf16x8*>(&sA[wm + 16 * i + l16][8 * quad]);
#pragma unroll
        for (int f = 0; f < 4; f++)
            bf[f] = *reinterpret_cast<const bf16x8*>(&sB[wn + 16 * f + l16][8 * quad]);
#pragma unroll
        for (int i = 0; i < 4; i++)
#pragma unroll
            for (int f = 0; f < 4; f++)
                acc[i][f] = __builtin_amdgcn_mfma_f32_16x16x32_bf16(af[i], bf[f], acc[i][f], 0, 0, 0);
        __syncthreads();
    }

#pragma unroll
    for (int i = 0; i < 4; i++) {
#pragma unroll
        for (int f = 0; f < 4; f++) {
            int ncol = bn + wn + 16 * f + l16;
            int mat = ncol >> 10, nc = ncol & 1023;
            float* Cb = C + (size_t)mat * (2048u * 1024u) + nc;
            int mrow = bm + wm + 16 * i + 4 * quad;
#pragma unroll
            for (int reg = 0; reg < 4; reg++)
                Cb[(size_t)(mrow + reg) * 1024] = acc[i][f][reg];
        }
    }
}

// ---------------------------------------------------------------------------
// Inclusive cumsum of g over t per (b,h) via wave-scan (2 barriers).
// Also transposes beta to [b,h,t].
// ---------------------------------------------------------------------------
__global__ __launch_bounds__(256) void cumsum_g(const float* __restrict__ g_in,
                                                const float* __restrict__ beta_in,
                                                float* __restrict__ G_out,
                                                float* __restrict__ betaT)
{
    __shared__ float wtot[4];
    int bh = blockIdx.x;            // 0..31
    int b = bh >> 4, h = bh & 15;
    int tid = threadIdx.x;          // 0..255
    int wv = tid >> 6, lane = tid & 63;
    int t4 = tid * 4;
    size_t src = ((size_t)(b * T_LEN) + t4) * NH + h;
    float g0 = g_in[src], g1 = g_in[src + NH], g2 = g_in[src + 2 * NH], g3 = g_in[src + 3 * NH];
    float b0 = beta_in[src], b1 = beta_in[src + NH], b2 = beta_in[src + 2 * NH], b3 = beta_in[src + 3 * NH];
    float c1 = g0 + g1, c2 = c1 + g2, c3 = c2 + g3;
    float x = c3;
#pragma unroll
    for (int off = 1; off < 64; off <<= 1) {
        float y = __shfl_up(x, off);
        if (lane >= off) x += y;
    }
    float base = x - c3;            // exclusive prefix across lanes
    if (lane == 63) wtot[wv] = x;
    __syncthreads();
    float woff = 0.f;
#pragma unroll
    for (int q = 0; q < 4; q++) woff += (q < wv) ? wtot[q] : 0.f;
    base += woff;
    size_t dst = (size_t)bh * T_LEN + t4;
    G_out[dst]     = base + g0;
    G_out[dst + 1] = base + c1;
    G_out[dst + 2] = base + c2;
    G_out[dst + 3] = base + c3;
    betaT[dst] = b0; betaT[dst + 1] = b1; betaT[dst + 2] = b2; betaT[dst + 3] = b3;
}

// ---------------------------------------------------------------------------
// Fused causal depthwise conv (K=4) + silu + per-head l2norm for q AND k.
// ---------------------------------------------------------------------------
__global__ __launch_bounds__(256) void conv_silu_l2(const float* __restrict__ qpre,
                                                    const float* __restrict__ kpre,
                                                    const float* __restrict__ Wcq,
                                                    const float* __restrict__ Wck,
                                                    float* __restrict__ qbuf,
                                                    float* __restrict__ kbuf)
{
    int gidAll = blockIdx.x * 4 + (threadIdx.x >> 6);
    int which = gidAll >> 15;                 // 0 = q, 1 = k
    int gid = gidAll & 32767;
    const float* pre = which ? kpre : qpre;
    const float* Wc  = which ? Wck : Wcq;
    float* out       = which ? kbuf : qbuf;
    int lane = threadIdx.x & 63;
    int h = gid & 15;
    int t = (gid >> 4) & (T_LEN - 1);
    int b = gid >> 14;
    int c = h * DKV + lane;
    float acc = 0.f;
#pragma unroll
    for (int i = 0; i < KCONV; i++) {
        int ts = t - (KCONV - 1) + i;
        if (ts >= 0)
            acc += pre[((size_t)(b * T_LEN) + ts) * HIDN + c] * Wc[c * KCONV + i];
    }
    float y = acc / (1.f + expf(-acc));
    float ss = y * y;
#pragma unroll
    for (int m = 1; m < 64; m <<= 1) ss += __shfl_xor(ss, m);
    out[((size_t)(b * T_LEN) + t) * HIDN + c] = y * rsqrtf(ss + 1e-6f);
}

// ---------------------------------------------------------------------------
// Stage 1: per-chunk local contributions (fully parallel).
// ---------------------------------------------------------------------------
__global__ __launch_bounds__(256) void chunk_local(const float* __restrict__ kbuf,
                                                   const float* __restrict__ vbuf,
                                                   const float* __restrict__ G,
                                                   const float* __restrict__ betaT,
                                                   float* __restrict__ Akk,
                                                   float* __restrict__ AkvT)
{
    __shared__ float sK[CC][PAD];
    __shared__ float sV[CC][PAD];
    __shared__ float sW[CC];
    int bid = blockIdx.x;                 // 2048
    int half = bid & 1;
    int cidx = bid >> 1;
    int chunk = cidx & (NC - 1), bh = cidx >> 5;
    int b = bh >> 4, h = bh & 15;
    int tid = threadIdx.x;
    int i = half * 32 + (tid >> 3);
    int j0 = (tid & 7) * 8;
    int ls = tid >> 3, ld = (tid & 7) * 8;
    int t0 = chunk * CC;

    {
        size_t ga = (((size_t)(b * T_LEN) + t0 + ls) * NH + h) * 64 + ld;
        *reinterpret_cast<float4*>(&sK[ls][ld])     = *reinterpret_cast<const float4*>(&kbuf[ga]);
        *reinterpret_cast<float4*>(&sK[ls][ld + 4]) = *reinterpret_cast<const float4*>(&kbuf[ga + 4]);
        *reinterpret_cast<float4*>(&sV[ls][ld])     = *reinterpret_cast<const float4*>(&vbuf[ga]);
        *reinterpret_cast<float4*>(&sV[ls][ld + 4]) = *reinterpret_cast<const float4*>(&vbuf[ga + 4]);
        if (tid < CC) {
            float gv = G[(size_t)bh * T_LEN + t0 + tid];
            float bv = betaT[(size_t)bh * T_LEN + t0 + tid];
            float gend = __shfl(gv, 31);
            sW[tid] = expf(gend - gv) * bv;
        }
    }
    __syncthreads();

    float akk[8], akv[8];
#pragma unroll
    for (int j = 0; j < 8; j++) { akk[j] = 0.f; akv[j] = 0.f; }
#pragma unroll 4
    for (int s = 0; s < CC; s++) {
        float wk = sW[s] * sK[s][i];
        float wv = sW[s] * sV[s][i];
        float4 ka = *reinterpret_cast<const float4*>(&sK[s][j0]);
        float4 kb = *reinterpret_cast<const float4*>(&sK[s][j0 + 4]);
        akk[0] += wk * ka.x; akk[1] += wk * ka.y; akk[2] += wk * ka.z; akk[3] += wk * ka.w;
        akk[4] += wk * kb.x; akk[5] += wk * kb.y; akk[6] += wk * kb.z; akk[7] += wk * kb.w;
        akv[0] += wv * ka.x; akv[1] += wv * ka.y; akv[2] += wv * ka.z; akv[3] += wv * ka.w;
        akv[4] += wv * kb.x; akv[5] += wv * kb.y; akv[6] += wv * kb.z; akv[7] += wv * kb.w;
    }
    size_t ob = ((size_t)cidx * 64 + i) * 64 + j0;
    *reinterpret_cast<float4*>(&Akk[ob])      = make_float4(akk[0], akk[1], akk[2], akk[3]);
    *reinterpret_cast<float4*>(&Akk[ob + 4])  = make_float4(akk[4], akk[5], akk[6], akk[7]);
    *reinterpret_cast<float4*>(&AkvT[ob])     = make_float4(akv[0], akv[1], akv[2], akv[3]);
    *reinterpret_cast<float4*>(&AkvT[ob + 4]) = make_float4(akv[4], akv[5], akv[6], akv[7]);
}

// ---------------------------------------------------------------------------
// Stage 2: element-parallel prefix over chunks, 4-batched loads.
// Hkk emitted as BF16 into Hkk_bf (fits qpre exactly, 8 MB);
// HkvT converted fp32 in-place.
// ---------------------------------------------------------------------------
__global__ __launch_bounds__(256) void chunk_prefix(const float* __restrict__ Akk,
                                                    float* __restrict__ HkvT,
                                                    const float* __restrict__ G,
                                                    unsigned short* __restrict__ Hkk_bf)
{
    __shared__ float sDec[NC];
    int blk = blockIdx.x;                 // 256
    int bh = blk >> 3, sub = blk & 7;
    int tid = threadIdx.x;
    if (tid < NC)
        sDec[tid] = (tid > 0)
            ? expf(G[(size_t)bh * T_LEN + tid * CC + CC - 1] - G[(size_t)bh * T_LEN + tid * CC - 1])
            : 1.f;
    __syncthreads();
    int flat = sub * 256 + tid;           // 0..2047
    int mat = flat >> 10, e4 = flat & 1023;
    float4 state = make_float4(0.f, 0.f, 0.f, 0.f);
    if (mat == 0) {
        const float* src = Akk + (size_t)bh * NC * 4096 + (size_t)e4 * 4;
        unsigned short* dst = Hkk_bf + (size_t)bh * NC * 4096 + (size_t)e4 * 4;
#pragma unroll 1
        for (int c0 = 0; c0 < NC; c0 += 4) {
            float4 av[4];
#pragma unroll
            for (int e = 0; e < 4; e++)
                av[e] = *reinterpret_cast<const float4*>(src + (size_t)(c0 + e) * 4096);
#pragma unroll
            for (int e = 0; e < 4; e++) {
                u16x4 o;
                o.x = f2bf(state.x); o.y = f2bf(state.y); o.z = f2bf(state.z); o.w = f2bf(state.w);
                *reinterpret_cast<u16x4*>(dst + (size_t)(c0 + e) * 4096) = o;
                float d = sDec[c0 + e];
                state.x = d * state.x + av[e].x;
                state.y = d * state.y + av[e].y;
                state.z = d * state.z + av[e].z;
                state.w = d * state.w + av[e].w;
            }
        }
    } else {
        float* base = HkvT + (size_t)bh * NC * 4096 + (size_t)e4 * 4;
#pragma unroll 1
        for (int c0 = 0; c0 < NC; c0 += 4) {
            float4 av[4];
#pragma unroll
            for (int e = 0; e < 4; e++)
                av[e] = *reinterpret_cast<const float4*>(base + (size_t)(c0 + e) * 4096);
#pragma unroll
            for (int e = 0; e < 4; e++) {
                *reinterpret_cast<float4*>(base + (size_t)(c0 + e) * 4096) = state;
                float d = sDec[c0 + e];
                state.x = d * state.x + av[e].x;
                state.y = d * state.y + av[e].y;
                state.z = d * state.z + av[e].z;
                state.w = d * state.w + av[e].w;
            }
        }
    }
}

// ---------------------------------------------------------------------------
// MFMA scan: ONE WAVE per (bh, chunk, half16) -> 2048 waves, 512 blocks.
// ---------------------------------------------------------------------------
__global__ __launch_bounds__(256, 2) void scan_mfma(
    const float* __restrict__ qbuf, const float* __restrict__ kbuf,
    const float* __restrict__ vbuf, const float* __restrict__ G,
    const float* __restrict__ betaT, const unsigned short* __restrict__ Hkk_bf,
    const float* __restrict__ HkvT0, const float* __restrict__ lambda_p,
    const float* __restrict__ norm_w, unsigned short* __restrict__ obf)
{
    __shared__ __align__(16) unsigned short sP[4][16][72];
    __shared__ __align__(16) unsigned short sM[4][16][40];

    const int tid = threadIdx.x;
    const int wv = tid >> 6, lane = tid & 63;
    const int quad = lane >> 4, l16 = lane & 15;
    const int W = blockIdx.x * 4 + wv;          // 0..2047
    const int half = W & 1;
    const int cidx = W >> 1;                    // 0..1023
    const int bh = cidx >> 5, chunk = cidx & 31;
    const int b = bh >> 4, h = bh & 15;
    const int t0 = chunk * CC;
    const int rbofs = 16 * half + 4 * quad;     // +reg -> local t-row
    unsigned short (*sPw)[72] = sP[wv];
    unsigned short (*sMw)[40] = sM[wv];

    const size_t rbase = ((size_t)(b * T_LEN + t0) * NH + h) * 64;
    const float* Gb = G + (size_t)bh * T_LEN + t0;
    const float* Bb = betaT + (size_t)bh * T_LEN + t0;
    const float Gprev = (chunk > 0) ? Gb[-1] : 0.f;

    float Gt[4], et[4];
#pragma unroll
    for (int reg = 0; reg < 4; reg++) {
        float g = Gb[rbofs + reg];
        Gt[reg] = g;
        et[reg] = expf(g - Gprev);
    }
    float Co[2][4];
#pragma unroll
    for (int sn = 0; sn < 2; sn++) {
        int s = 16 * sn + l16;
        float Gs = Gb[s], bts = Bb[s];
#pragma unroll
        for (int reg = 0; reg < 4; reg++) {
            int t = rbofs + reg;
            Co[sn][reg] = (s <= t) ? expf(Gt[reg] - Gs) * bts : 0.f;
        }
    }
    float lam[4], nw[4];
#pragma unroll
    for (int f = 0; f < 4; f++) {
        lam[f] = softplusf(lambda_p[h * 64 + 16 * f + l16]) + 0.25f;
        nw[f]  = norm_w[16 * f + l16];
    }

    bf16x8 Kb[2][2];
#pragma unroll
    for (int sn = 0; sn < 2; sn++) {
        const float* kr = kbuf + rbase + (size_t)(16 * sn + l16) * 1024;
#pragma unroll
        for (int ks = 0; ks < 2; ks++) {
            float4 a = *reinterpret_cast<const float4*>(kr + 8 * quad + 32 * ks);
            float4 c = *reinterpret_cast<const float4*>(kr + 8 * quad + 32 * ks + 4);
            Kb[sn][ks] = pack8(a, c);
        }
    }
    bf16x8 KTb[4];
#pragma unroll
    for (int f = 0; f < 4; f++) {
        union { bf16x8 v; unsigned short u[8]; } r;
#pragma unroll
        for (int j = 0; j < 8; j++)
            r.u[j] = f2bf(kbuf[rbase + (size_t)(8 * quad + j) * 1024 + 16 * f + l16]);
        KTb[f] = r.v;
    }
    const size_t hbase = ((size_t)(bh * NC) + chunk) * 4096;
    bf16x8 Hb[4][2];
#pragma unroll
    for (int f = 0; f < 4; f++) {
        const unsigned short* hr = Hkk_bf + hbase + (size_t)(16 * f + l16) * 64;
#pragma unroll
        for (int ks = 0; ks < 2; ks++)
            Hb[f][ks] = *reinterpret_cast<const bf16x8*>(hr + 8 * quad + 32 * ks);
    }

    f32x4 X[4], R[4], P[4];
    float rs8[4];
#pragma unroll
    for (int reg = 0; reg < 4; reg++) rs8[reg] = 0.f;
#pragma unroll
    for (int f = 0; f < 4; f++) {
#pragma unroll
        for (int reg = 0; reg < 4; reg++) {
            float q = qbuf[rbase + (size_t)(rbofs + reg) * 1024 + 16 * f + l16];
            P[f][reg] = q; R[f][reg] = q; X[f][reg] = 0.f;
            rs8[reg] += q * q;
        }
    }
#pragma unroll
    for (int reg = 0; reg < 4; reg++) {
        float v = rs8[reg];
        v += __shfl_xor(v, 1); v += __shfl_xor(v, 2);
        v += __shfl_xor(v, 4); v += __shfl_xor(v, 8);
        rs8[reg] = v;
    }

    const f32x4 zero4 = {0.f, 0.f, 0.f, 0.f};

#pragma unroll 1
    for (int it = 0; it < CG_IT; it++) {
#pragma unroll
        for (int reg = 0; reg < 4; reg++)
#pragma unroll
            for (int f = 0; f < 4; f++)
                sPw[4 * quad + reg][16 * f + l16] = f2bf(P[f][reg]);
        __threadfence_block();
        bf16x8 Pa[2];
#pragma unroll
        for (int ks = 0; ks < 2; ks++)
            Pa[ks] = *reinterpret_cast<const bf16x8*>(&sPw[l16][8 * quad + 32 * ks]);
        f32x4 D[2];
#pragma unroll
        for (int sn = 0; sn < 2; sn++) {
            f32x4 d = __builtin_amdgcn_mfma_f32_16x16x32_bf16(Pa[0], Kb[sn][0], zero4, 0, 0, 0);
            D[sn] = __builtin_amdgcn_mfma_f32_16x16x32_bf16(Pa[1], Kb[sn][1], d, 0, 0, 0);
        }
#pragma unroll
        for (int sn = 0; sn < 2; sn++)
#pragma unroll
            for (int reg = 0; reg < 4; reg++)
                sMw[4 * quad + reg][16 * sn + l16] = f2bf(Co[sn][reg] * D[sn][reg]);
        __threadfence_block();
        bf16x8 Ma = *reinterpret_cast<const bf16x8*>(&sMw[l16][8 * quad]);
        f32x4 AP[4], A2[4];
#pragma unroll
        for (int f = 0; f < 4; f++) {
            AP[f] = __builtin_amdgcn_mfma_f32_16x16x32_bf16(Ma, KTb[f], zero4, 0, 0, 0);
            f32x4 a = __builtin_amdgcn_mfma_f32_16x16x32_bf16(Pa[0], Hb[f][0], zero4, 0, 0, 0);
            A2[f] = __builtin_amdgcn_mfma_f32_16x16x32_bf16(Pa[1], Hb[f][1], a, 0, 0, 0);
        }
#pragma unroll
        for (int f = 0; f < 4; f++)
#pragma unroll
            for (int reg = 0; reg < 4; reg++)
                AP[f][reg] = lam[f] * P[f][reg] + AP[f][reg] + et[reg] * A2[f][reg];
        float alpha[4], rsn[4];
#pragma unroll
        for (int reg = 0; reg < 4; reg++) {
            float s = 0.f;
#pragma unroll
            for (int f = 0; f < 4; f++) s += P[f][reg] * AP[f][reg];
            s += __shfl_xor(s, 1); s += __shfl_xor(s, 2);
            s += __shfl_xor(s, 4); s += __shfl_xor(s, 8);
            alpha[reg] = rs8[reg] / (s + 1e-12f);
            rsn[reg] = 0.f;
        }
#pragma unroll
        for (int f = 0; f < 4; f++)
#pragma unroll
            for (int reg = 0; reg < 4; reg++) {
                X[f][reg] += alpha[reg] * P[f][reg];
                float rv = R[f][reg] - alpha[reg] * AP[f][reg];
                R[f][reg] = rv;
                rsn[reg] += rv * rv;
            }
#pragma unroll
        for (int reg = 0; reg < 4; reg++) {
            float v = rsn[reg];
            v += __shfl_xor(v, 1); v += __shfl_xor(v, 2);
            v += __shfl_xor(v, 4); v += __shfl_xor(v, 8);
            float btac = v / (rs8[reg] + 1e-12f);
            rs8[reg] = v;
#pragma unroll
            for (int f = 0; f < 4; f++)
                P[f][reg] = R[f][reg] + btac * P[f][reg];
        }
    }

    // ---- output phase ----
#pragma unroll
    for (int reg = 0; reg < 4; reg++)
#pragma unroll
        for (int f = 0; f < 4; f++)
            sPw[4 * quad + reg][16 * f + l16] = f2bf(X[f][reg]);
    __threadfence_block();
    bf16x8 Xa[2];
#pragma unroll
    for (int ks = 0; ks < 2; ks++)
        Xa[ks] = *reinterpret_cast<const bf16x8*>(&sPw[l16][8 * quad + 32 * ks]);
    f32x4 Do[2];
#pragma unroll
    for (int sn = 0; sn < 2; sn++) {
        f32x4 d = __builtin_amdgcn_mfma_f32_16x16x32_bf16(Xa[0], Kb[sn][0], zero4, 0, 0, 0);
        Do[sn] = __builtin_amdgcn_mfma_f32_16x16x32_bf16(Xa[1], Kb[sn][1], d, 0, 0, 0);
    }
#pragma unroll
    for (int sn = 0; sn < 2; sn++)
#pragma unroll
        for (int reg = 0; reg < 4; reg++)
            sMw[4 * quad + reg][16 * sn + l16] = f2bf(Co[sn][reg] * Do[sn][reg]);
    __threadfence_block();
    bf16x8 Mo = *reinterpret_cast<const bf16x8*>(&sMw[l16][8 * quad]);
    bf16x8 Vb[4];
#pragma unroll
    for (int f = 0; f < 4; f++) {
        union { bf16x8 v; unsigned short u[8]; } r;
#pragma unroll
        for (int j = 0; j < 8; j++)
            r.u[j] = f2bf(vbuf[rbase + (size_t)(8 * quad + j) * 1024 + 16 * f + l16]);
        Vb[f] = r.v;
    }
    bf16x8 Hvb[4][2];
#pragma unroll
    for (int f = 0; f < 4; f++) {
        const float* hr = HkvT0 + hbase + (size_t)(16 * f + l16) * 64;
#pragma unroll
        for (int ks = 0; ks < 2; ks++) {
            float4 a = *reinterpret_cast<const float4*>(hr + 8 * quad + 32 * ks);
            float4 c = *reinterpret_cast<const float4*>(hr + 8 * quad + 32 * ks + 4);
            Hvb[f][ks] = pack8(a, c);
        }
    }
    f32x4 O[4];
#pragma unroll
    for (int f = 0; f < 4; f++) {
        f32x4 o1 = __builtin_amdgcn_mfma_f32_16x16x32_bf16(Mo, Vb[f], zero4, 0, 0, 0);
        f32x4 o2 = __builtin_amdgcn_mfma_f32_16x16x32_bf16(Xa[0], Hvb[f][0], zero4, 0, 0, 0);
        o2 = __builtin_amdgcn_mfma_f32_16x16x32_bf16(Xa[1], Hvb[f][1], o2, 0, 0, 0);
#pragma unroll
        for (int reg = 0; reg < 4; reg++)
            O[f][reg] = o1[reg] + et[reg] * o2[reg];
    }
#pragma unroll
    for (int reg = 0; reg < 4; reg++) {
        float s = 0.f;
#pragma unroll
        for (int f = 0; f < 4; f++) s += O[f][reg] * O[f][reg];
        s += __shfl_xor(s, 1); s += __shfl_xor(s, 2);
        s += __shfl_xor(s, 4); s += __shfl_xor(s, 8);
        float scale = rsqrtf(s * (1.f / 64.f) + 1e-5f);
        size_t orow = rbase + (size_t)(rbofs + reg) * 1024;
#pragma unroll
        for (int f = 0; f < 4; f++)
            obf[orow + 16 * f + l16] = f2bf(O[f][reg] * scale * nw[f]);
    }
}

// ---------------------------------------------------------------------------
extern "C" void kernel_launch(void* const* d_in, const int* in_sizes, int n_in,
                              void* d_out, int out_size, void* d_ws, size_t ws_size,
                              hipStream_t stream)
{
    const float* hidden   = (const float*)d_in[0];
    const float* Wq       = (const float*)d_in[1];
    const float* Wk       = (const float*)d_in[2];
    const float* Wv       = (const float*)d_in[3];
    const float* Wa       = (const float*)d_in[4];
    const float* Wb       = (const float*)d_in[5];
    const float* bb       = (const float*)d_in[6];
    const float* A_log    = (const float*)d_in[7];
    const float* dt_bias  = (const float*)d_in[8];
    const float* lambda_p = (const float*)d_in[9];
    const float* Wconv_q  = (const float*)d_in[10];
    const float* Wconv_k  = (const float*)d_in[11];
    const float* norm_w   = (const float*)d_in[12];
    const float* Wo       = (const float*)d_in[13];
    float* out = (float*)d_out;

    float* ws = (float*)d_ws;
    const size_t SZ_BIG = (size_t)2 * T_LEN * HIDN;   // 2M floats (8 MB)
    float* qpre = ws;
    float* kpre = qpre + SZ_BIG;
    float* vbuf = kpre + SZ_BIG;
    float* qbuf = vbuf + SZ_BIG;
    float* kbuf = qbuf + SZ_BIG;
    float* gbuf = kbuf + SZ_BIG;
    float* bbuf = gbuf + 32768;
    float* Gbuf = bbuf + 32768;
    float* btT  = Gbuf + 32768;
    float* Akk  = btT + 32768;                        // 4M floats (16 MB)
    float* AkvT = Akk + (size_t)32 * NC * 4096;       // 4M floats -> HkvT in-place
    unsigned short* WoT = (unsigned short*)(AkvT + (size_t)32 * NC * 4096);

    unsigned short* hidden_bf = (unsigned short*)AkvT;    // dead before chunk_local
    unsigned short* WqkvT = (unsigned short*)Akk;         // dead before chunk_local
    unsigned short* obuf_bf = (unsigned short*)kpre;      // kpre dead after conv
    unsigned short* Hkk_bf = (unsigned short*)qpre;       // qpre dead after conv (8 MB exact fit)

    const int M = 2 * T_LEN;                          // 2048

    prep<<<3072, 256, 0, stream>>>(hidden, Wq, Wk, Wv, Wo, hidden_bf, WqkvT, WoT);
    proj_gb<<<M / 4, 256, 0, stream>>>(hidden, Wa, Wb, bb, A_log, dt_bias, gbuf, bbuf);

    dim3 gq(3 * HIDN / 128, M / 128);                 // (24, 16)
    gemm_qkv128<<<gq, 256, 0, stream>>>(hidden_bf, WqkvT, qpre);
    cumsum_g<<<32, 256, 0, stream>>>(gbuf, bbuf, Gbuf, btT);
    conv_silu_l2<<<2 * M * NH / 4, 256, 0, stream>>>(qpre, kpre, Wconv_q, Wconv_k,
                                                     qbuf, kbuf);
    chunk_local<<<2048, 256, 0, stream>>>(kbuf, vbuf, Gbuf, btT, Akk, AkvT);
    chunk_prefix<<<256, 256, 0, stream>>>(Akk, AkvT, Gbuf, Hkk_bf);
    scan_mfma<<<512, 256, 0, stream>>>(qbuf, kbuf, vbuf, Gbuf, btT, Hkk_bf, AkvT,
                                       lambda_p, norm_w, obuf_bf);
    dim3 gg(HIDN / 64, M / 64);
    gemm_bf16<<<gg, 256, 0, stream>>>(obuf_bf, WoT, out, M, HIDN, HIDN);
}

// Round 12
// 249.325 us; speedup vs baseline: 1.2059x; 1.0067x over previous
//
#include <hip/hip_runtime.h>
#include <hip/hip_bf16.h>
#include <stdint.h>

#define T_LEN 1024
#define HIDN  1024
#define NH    16
#define DKV   64
#define KCONV 4
#define CG_IT 15
#define CC    32              // chunk length
#define NC    (T_LEN / CC)    // 32 chunks
#define PAD   68              // padded row stride (fp32 LDS tiles)

typedef __attribute__((ext_vector_type(8))) short          bf16x8;
typedef __attribute__((ext_vector_type(8))) unsigned short u16x8;
typedef __attribute__((ext_vector_type(4))) unsigned short u16x4;
typedef __attribute__((ext_vector_type(4))) float          f32x4;

__device__ __forceinline__ float softplusf(float x) {
    return x > 20.f ? x : log1pf(expf(x));
}
__device__ __forceinline__ unsigned short f2bf(float x) {
    __hip_bfloat16 b = __float2bfloat16(x);
    return *reinterpret_cast<unsigned short*>(&b);
}
__device__ __forceinline__ bf16x8 pack8(float4 a, float4 b) {
    union { bf16x8 v; unsigned short u[8]; } r;
    r.u[0] = f2bf(a.x); r.u[1] = f2bf(a.y); r.u[2] = f2bf(a.z); r.u[3] = f2bf(a.w);
    r.u[4] = f2bf(b.x); r.u[5] = f2bf(b.y); r.u[6] = f2bf(b.z); r.u[7] = f2bf(b.w);
    return r.v;
}

// 16-lane sum via DPP (VALU pipe, no DS latency).  Steps: xor1, xor2 (bit-
// identical to butterfly), then row_ror:4 + row_ror:8 (adds the other quads'
// sums -- value-equal regrouping).
__device__ __forceinline__ float wsum16(float x) {
    union { float f; int i; } a, b;
    a.f = x; b.i = __builtin_amdgcn_update_dpp(0, a.i, 0xB1, 0xF, 0xF, true); x += b.f;
    a.f = x; b.i = __builtin_amdgcn_update_dpp(0, a.i, 0x4E, 0xF, 0xF, true); x += b.f;
    a.f = x; b.i = __builtin_amdgcn_update_dpp(0, a.i, 0x124, 0xF, 0xF, true); x += b.f;
    a.f = x; b.i = __builtin_amdgcn_update_dpp(0, a.i, 0x128, 0xF, 0xF, true); x += b.f;
    return x;
}

// ---------------------------------------------------------------------------
// prep: blocks [0,2048) cast hidden fp32->bf16; blocks [2048,3072)
// transpose+cast the four weight matrices.
// ---------------------------------------------------------------------------
__global__ __launch_bounds__(256) void prep(const float* __restrict__ hidden,
                                            const float* __restrict__ Wq,
                                            const float* __restrict__ Wk,
                                            const float* __restrict__ Wv,
                                            const float* __restrict__ Wo,
                                            unsigned short* __restrict__ hidden_bf,
                                            unsigned short* __restrict__ WqkvT,
                                            unsigned short* __restrict__ WoT)
{
    __shared__ unsigned short sT[64][68];
    int blk = blockIdx.x;
    int tid = threadIdx.x;
    if (blk < 2048) {
        int i = blk * 256 + tid;
        float4 v = *reinterpret_cast<const float4*>(hidden + (size_t)i * 4);
        u16x4 o;
        o.x = f2bf(v.x); o.y = f2bf(v.y); o.z = f2bf(v.z); o.w = f2bf(v.w);
        *reinterpret_cast<u16x4*>(hidden_bf + (size_t)i * 4) = o;
        return;
    }
    int r = blk - 2048;                 // 0..1023
    int m = r >> 8;                     // matrix 0..3
    int local = r & 255;
    int n0 = (local & 15) * 64, k0 = (local >> 4) * 64;
    const float* W = (m == 0) ? Wq : (m == 1) ? Wk : (m == 2) ? Wv : Wo;
    unsigned short* WT = (m < 3) ? (WqkvT + (size_t)m * HIDN * HIDN) : WoT;

    int rr = tid >> 4, cc4 = (tid & 15) * 4;
#pragma unroll
    for (int p = 0; p < 4; p++) {
        int rw = p * 16 + rr;
        float4 v = *reinterpret_cast<const float4*>(&W[(size_t)(k0 + rw) * HIDN + n0 + cc4]);
        sT[cc4 + 0][rw] = f2bf(v.x);
        sT[cc4 + 1][rw] = f2bf(v.y);
        sT[cc4 + 2][rw] = f2bf(v.z);
        sT[cc4 + 3][rw] = f2bf(v.w);
    }
    __syncthreads();
#pragma unroll
    for (int p = 0; p < 4; p++) {
        int rw = p * 16 + rr;
        u16x4 v = *reinterpret_cast<const u16x4*>(&sT[rw][cc4]);
        *reinterpret_cast<u16x4*>(&WT[(size_t)(n0 + rw) * HIDN + k0 + cc4]) = v;
    }
}

// ---------------------------------------------------------------------------
// g / beta projections: one wave per row, coalesced weight access.
// ---------------------------------------------------------------------------
__global__ __launch_bounds__(256) void proj_gb(const float* __restrict__ hidden,
                                               const float* __restrict__ Wa,
                                               const float* __restrict__ Wb,
                                               const float* __restrict__ bb,
                                               const float* __restrict__ A_log,
                                               const float* __restrict__ dt_bias,
                                               float* __restrict__ g_out,
                                               float* __restrict__ beta_out)
{
    int wvid = threadIdx.x >> 6, lane = threadIdx.x & 63;
    int row = blockIdx.x * 4 + wvid;            // 0..2047
    const float* hr = hidden + (size_t)row * HIDN;

    float da[16], db[16];
#pragma unroll
    for (int h = 0; h < 16; h++) { da[h] = 0.f; db[h] = 0.f; }

#pragma unroll 4
    for (int j = 0; j < 16; j++) {
        int i = j * 64 + lane;
        float x = hr[i];
        const float4* wa4 = reinterpret_cast<const float4*>(Wa + (size_t)i * NH);
        const float4* wb4 = reinterpret_cast<const float4*>(Wb + (size_t)i * NH);
#pragma unroll
        for (int q = 0; q < 4; q++) {
            float4 wa = wa4[q], wb = wb4[q];
            da[q * 4 + 0] += x * wa.x; da[q * 4 + 1] += x * wa.y;
            da[q * 4 + 2] += x * wa.z; da[q * 4 + 3] += x * wa.w;
            db[q * 4 + 0] += x * wb.x; db[q * 4 + 1] += x * wb.y;
            db[q * 4 + 2] += x * wb.z; db[q * 4 + 3] += x * wb.w;
        }
    }
#pragma unroll
    for (int m = 1; m < 64; m <<= 1) {
#pragma unroll
        for (int h = 0; h < 16; h++) {
            da[h] += __shfl_xor(da[h], m);
            db[h] += __shfl_xor(db[h], m);
        }
    }
    float dah = 0.f, dbh = 0.f;
#pragma unroll
    for (int h = 0; h < 16; h++) {
        bool sel = (lane == h);
        dah = sel ? da[h] : dah;
        dbh = sel ? db[h] : dbh;
    }
    if (lane < 16) {
        float sp = softplusf(dah + dt_bias[lane]);
        g_out[row * NH + lane]    = -expf(A_log[lane]) * sp;
        beta_out[row * NH + lane] = 1.f / (1.f + expf(-(dbh + bb[lane])));
    }
}

// ---------------------------------------------------------------------------
// bf16 MFMA GEMM (TN): C[M,N] = A[M,K] @ B^T, Bt is [N][K].  64x64 tile.
// (output projection)
// ---------------------------------------------------------------------------
__global__ __launch_bounds__(256) void gemm_bf16(const unsigned short* __restrict__ A,
                                                 const unsigned short* __restrict__ Bt,
                                                 float* __restrict__ C,
                                                 int M, int N, int K)
{
    __shared__ unsigned short sA[64][40];
    __shared__ unsigned short sB[64][40];
    const int tid = threadIdx.x;
    const int bm = blockIdx.y * 64, bn = blockIdx.x * 64;
    const int w = tid >> 6, lane = tid & 63;
    const int l16 = lane & 15, quad = lane >> 4;
    const int lrow = tid >> 2, lk = (tid & 3) * 8;

    f32x4 acc[4];
#pragma unroll
    for (int f = 0; f < 4; f++) acc[f] = (f32x4){0.f, 0.f, 0.f, 0.f};

    const size_t arow = (size_t)(bm + lrow) * K;
    const size_t brow = (size_t)(bn + lrow) * K;

    for (int k0 = 0; k0 < K; k0 += 32) {
        u16x8 av = *reinterpret_cast<const u16x8*>(A + arow + k0 + lk);
        u16x8 bv = *reinterpret_cast<const u16x8*>(Bt + brow + k0 + lk);
        *reinterpret_cast<u16x8*>(&sA[lrow][lk]) = av;
        *reinterpret_cast<u16x8*>(&sB[lrow][lk]) = bv;
        __syncthreads();

        bf16x8 aF = *reinterpret_cast<const bf16x8*>(&sA[w * 16 + l16][quad * 8]);
#pragma unroll
        for (int f = 0; f < 4; f++) {
            bf16x8 bF = *reinterpret_cast<const bf16x8*>(&sB[f * 16 + l16][quad * 8]);
            acc[f] = __builtin_amdgcn_mfma_f32_16x16x32_bf16(aF, bF, acc[f], 0, 0, 0);
        }
        __syncthreads();
    }

#pragma unroll
    for (int f = 0; f < 4; f++) {
#pragma unroll
        for (int i = 0; i < 4; i++) {
            int m = bm + w * 16 + quad * 4 + i;
            C[(size_t)m * N + bn + f * 16 + l16] = acc[f][i];
        }
    }
}

// ---------------------------------------------------------------------------
// Merged q/k/v GEMM, 128x128 tile, BK=32.
// ---------------------------------------------------------------------------
__global__ __launch_bounds__(256) void gemm_qkv128(const unsigned short* __restrict__ A,
                                                   const unsigned short* __restrict__ Bt,
                                                   float* __restrict__ C)
{
    const int K = 1024;
    __shared__ unsigned short sA[128][40];
    __shared__ unsigned short sB[128][40];
    const int tid = threadIdx.x;
    const int bm = blockIdx.y * 128;
    const int bn = blockIdx.x * 128;
    const int w = tid >> 6, lane = tid & 63;
    const int l16 = lane & 15, quad = lane >> 4;
    const int wm = (w >> 1) * 64, wn = (w & 1) * 64;
    const int lrow = tid >> 1, lk = (tid & 1) * 16;

    f32x4 acc[4][4];
#pragma unroll
    for (int i = 0; i < 4; i++)
#pragma unroll
        for (int f = 0; f < 4; f++) acc[i][f] = (f32x4){0.f, 0.f, 0.f, 0.f};

    const size_t arow = (size_t)(bm + lrow) * K + lk;
    const size_t brow = (size_t)(bn + lrow) * K + lk;

    for (int k0 = 0; k0 < K; k0 += 32) {
        u16x8 a0 = *reinterpret_cast<const u16x8*>(A + arow + k0);
        u16x8 a1 = *reinterpret_cast<const u16x8*>(A + arow + k0 + 8);
        u16x8 b0 = *reinterpret_cast<const u16x8*>(Bt + brow + k0);
        u16x8 b1 = *reinterpret_cast<const u16x8*>(Bt + brow + k0 + 8);
        *reinterpret_cast<u16x8*>(&sA[lrow][lk])     = a0;
        *reinterpret_cast<u16x8*>(&sA[lrow][lk + 8]) = a1;
        *reinterpret_cast<u16x8*>(&sB[lrow][lk])     = b0;
        *reinterpret_cast<u16x8*>(&sB[lrow][lk + 8]) = b1;
        __syncthreads();

        bf16x8 af[4], bf[4];
#pragma unroll
        for (int i = 0; i < 4; i++)
            af[i] = *reinterpret_cast<const bf16x8*>(&sA[wm + 16 * i + l16][8 * quad]);
#pragma unroll
        for (int f = 0; f < 4; f++)
            bf[f] = *reinterpret_cast<const bf16x8*>(&sB[wn + 16 * f + l16][8 * quad]);
#pragma unroll
        for (int i = 0; i < 4; i++)
#pragma unroll
            for (int f = 0; f < 4; f++)
                acc[i][f] = __builtin_amdgcn_mfma_f32_16x16x32_bf16(af[i], bf[f], acc[i][f], 0, 0, 0);
        __syncthreads();
    }

#pragma unroll
    for (int i = 0; i < 4; i++) {
#pragma unroll
        for (int f = 0; f < 4; f++) {
            int ncol = bn + wn + 16 * f + l16;
            int mat = ncol >> 10, nc = ncol & 1023;
            float* Cb = C + (size_t)mat * (2048u * 1024u) + nc;
            int mrow = bm + wm + 16 * i + 4 * quad;
#pragma unroll
            for (int reg = 0; reg < 4; reg++)
                Cb[(size_t)(mrow + reg) * 1024] = acc[i][f][reg];
        }
    }
}

// ---------------------------------------------------------------------------
// Inclusive cumsum of g over t per (b,h) via wave-scan (2 barriers).
// ---------------------------------------------------------------------------
__global__ __launch_bounds__(256) void cumsum_g(const float* __restrict__ g_in,
                                                const float* __restrict__ beta_in,
                                                float* __restrict__ G_out,
                                                float* __restrict__ betaT)
{
    __shared__ float wtot[4];
    int bh = blockIdx.x;            // 0..31
    int b = bh >> 4, h = bh & 15;
    int tid = threadIdx.x;          // 0..255
    int wv = tid >> 6, lane = tid & 63;
    int t4 = tid * 4;
    size_t src = ((size_t)(b * T_LEN) + t4) * NH + h;
    float g0 = g_in[src], g1 = g_in[src + NH], g2 = g_in[src + 2 * NH], g3 = g_in[src + 3 * NH];
    float b0 = beta_in[src], b1 = beta_in[src + NH], b2 = beta_in[src + 2 * NH], b3 = beta_in[src + 3 * NH];
    float c1 = g0 + g1, c2 = c1 + g2, c3 = c2 + g3;
    float x = c3;
#pragma unroll
    for (int off = 1; off < 64; off <<= 1) {
        float y = __shfl_up(x, off);
        if (lane >= off) x += y;
    }
    float base = x - c3;            // exclusive prefix across lanes
    if (lane == 63) wtot[wv] = x;
    __syncthreads();
    float woff = 0.f;
#pragma unroll
    for (int q = 0; q < 4; q++) woff += (q < wv) ? wtot[q] : 0.f;
    base += woff;
    size_t dst = (size_t)bh * T_LEN + t4;
    G_out[dst]     = base + g0;
    G_out[dst + 1] = base + c1;
    G_out[dst + 2] = base + c2;
    G_out[dst + 3] = base + c3;
    betaT[dst] = b0; betaT[dst + 1] = b1; betaT[dst + 2] = b2; betaT[dst + 3] = b3;
}

// ---------------------------------------------------------------------------
// Fused causal depthwise conv (K=4) + silu + per-head l2norm for q AND k.
// ---------------------------------------------------------------------------
__global__ __launch_bounds__(256) void conv_silu_l2(const float* __restrict__ qpre,
                                                    const float* __restrict__ kpre,
                                                    const float* __restrict__ Wcq,
                                                    const float* __restrict__ Wck,
                                                    float* __restrict__ qbuf,
                                                    float* __restrict__ kbuf)
{
    int gidAll = blockIdx.x * 4 + (threadIdx.x >> 6);
    int which = gidAll >> 15;                 // 0 = q, 1 = k
    int gid = gidAll & 32767;
    const float* pre = which ? kpre : qpre;
    const float* Wc  = which ? Wck : Wcq;
    float* out       = which ? kbuf : qbuf;
    int lane = threadIdx.x & 63;
    int h = gid & 15;
    int t = (gid >> 4) & (T_LEN - 1);
    int b = gid >> 14;
    int c = h * DKV + lane;
    float acc = 0.f;
#pragma unroll
    for (int i = 0; i < KCONV; i++) {
        int ts = t - (KCONV - 1) + i;
        if (ts >= 0)
            acc += pre[((size_t)(b * T_LEN) + ts) * HIDN + c] * Wc[c * KCONV + i];
    }
    float y = acc / (1.f + expf(-acc));
    float ss = y * y;
#pragma unroll
    for (int m = 1; m < 64; m <<= 1) ss += __shfl_xor(ss, m);
    out[((size_t)(b * T_LEN) + t) * HIDN + c] = y * rsqrtf(ss + 1e-6f);
}

// ---------------------------------------------------------------------------
// Stage 1: per-chunk local contributions.  ONE block per cidx (1024 blocks),
// each thread owns rows i and i+32 -> K/V staged once (half the fetch).
// Same per-output FMA order as before -> bit-identical.
// ---------------------------------------------------------------------------
__global__ __launch_bounds__(256) void chunk_local(const float* __restrict__ kbuf,
                                                   const float* __restrict__ vbuf,
                                                   const float* __restrict__ G,
                                                   const float* __restrict__ betaT,
                                                   float* __restrict__ Akk,
                                                   float* __restrict__ AkvT)
{
    __shared__ float sK[CC][PAD];
    __shared__ float sV[CC][PAD];
    __shared__ float sW[CC];
    int cidx = blockIdx.x;                // 1024 = bh*NC + chunk
    int chunk = cidx & (NC - 1), bh = cidx >> 5;
    int b = bh >> 4, h = bh & 15;
    int tid = threadIdx.x;
    int i = tid >> 3;                     // rows i and i+32
    int j0 = (tid & 7) * 8;
    int ls = tid >> 3, ld = (tid & 7) * 8;
    int t0 = chunk * CC;

    {
        size_t ga = (((size_t)(b * T_LEN) + t0 + ls) * NH + h) * 64 + ld;
        *reinterpret_cast<float4*>(&sK[ls][ld])     = *reinterpret_cast<const float4*>(&kbuf[ga]);
        *reinterpret_cast<float4*>(&sK[ls][ld + 4]) = *reinterpret_cast<const float4*>(&kbuf[ga + 4]);
        *reinterpret_cast<float4*>(&sV[ls][ld])     = *reinterpret_cast<const float4*>(&vbuf[ga]);
        *reinterpret_cast<float4*>(&sV[ls][ld + 4]) = *reinterpret_cast<const float4*>(&vbuf[ga + 4]);
        if (tid < CC) {
            float gv = G[(size_t)bh * T_LEN + t0 + tid];
            float bv = betaT[(size_t)bh * T_LEN + t0 + tid];
            float gend = __shfl(gv, 31);
            sW[tid] = expf(gend - gv) * bv;
        }
    }
    __syncthreads();

    float akk[2][8], akv[2][8];
#pragma unroll
    for (int e = 0; e < 2; e++)
#pragma unroll
        for (int j = 0; j < 8; j++) { akk[e][j] = 0.f; akv[e][j] = 0.f; }
#pragma unroll 4
    for (int s = 0; s < CC; s++) {
        float w = sW[s];
        float wk0 = w * sK[s][i],      wv0 = w * sV[s][i];
        float wk1 = w * sK[s][i + 32], wv1 = w * sV[s][i + 32];
        float4 ka = *reinterpret_cast<const float4*>(&sK[s][j0]);
        float4 kb = *reinterpret_cast<const float4*>(&sK[s][j0 + 4]);
        akk[0][0] += wk0 * ka.x; akk[0][1] += wk0 * ka.y; akk[0][2] += wk0 * ka.z; akk[0][3] += wk0 * ka.w;
        akk[0][4] += wk0 * kb.x; akk[0][5] += wk0 * kb.y; akk[0][6] += wk0 * kb.z; akk[0][7] += wk0 * kb.w;
        akk[1][0] += wk1 * ka.x; akk[1][1] += wk1 * ka.y; akk[1][2] += wk1 * ka.z; akk[1][3] += wk1 * ka.w;
        akk[1][4] += wk1 * kb.x; akk[1][5] += wk1 * kb.y; akk[1][6] += wk1 * kb.z; akk[1][7] += wk1 * kb.w;
        akv[0][0] += wv0 * ka.x; akv[0][1] += wv0 * ka.y; akv[0][2] += wv0 * ka.z; akv[0][3] += wv0 * ka.w;
        akv[0][4] += wv0 * kb.x; akv[0][5] += wv0 * kb.y; akv[0][6] += wv0 * kb.z; akv[0][7] += wv0 * kb.w;
        akv[1][0] += wv1 * ka.x; akv[1][1] += wv1 * ka.y; akv[1][2] += wv1 * ka.z; akv[1][3] += wv1 * ka.w;
        akv[1][4] += wv1 * kb.x; akv[1][5] += wv1 * kb.y; akv[1][6] += wv1 * kb.z; akv[1][7] += wv1 * kb.w;
    }
#pragma unroll
    for (int e = 0; e < 2; e++) {
        size_t ob = ((size_t)cidx * 64 + i + e * 32) * 64 + j0;
        *reinterpret_cast<float4*>(&Akk[ob])      = make_float4(akk[e][0], akk[e][1], akk[e][2], akk[e][3]);
        *reinterpret_cast<float4*>(&Akk[ob + 4])  = make_float4(akk[e][4], akk[e][5], akk[e][6], akk[e][7]);
        *reinterpret_cast<float4*>(&AkvT[ob])     = make_float4(akv[e][0], akv[e][1], akv[e][2], akv[e][3]);
        *reinterpret_cast<float4*>(&AkvT[ob + 4]) = make_float4(akv[e][4], akv[e][5], akv[e][6], akv[e][7]);
    }
}

// ---------------------------------------------------------------------------
// Stage 2: element-parallel prefix over chunks, 4-batched loads.
// Hkk emitted as BF16 into Hkk_bf; HkvT converted fp32 in-place.
// ---------------------------------------------------------------------------
__global__ __launch_bounds__(256) void chunk_prefix(const float* __restrict__ Akk,
                                                    float* __restrict__ HkvT,
                                                    const float* __restrict__ G,
                                                    unsigned short* __restrict__ Hkk_bf)
{
    __shared__ float sDec[NC];
    int blk = blockIdx.x;                 // 256
    int bh = blk >> 3, sub = blk & 7;
    int tid = threadIdx.x;
    if (tid < NC)
        sDec[tid] = (tid > 0)
            ? expf(G[(size_t)bh * T_LEN + tid * CC + CC - 1] - G[(size_t)bh * T_LEN + tid * CC - 1])
            : 1.f;
    __syncthreads();
    int flat = sub * 256 + tid;           // 0..2047
    int mat = flat >> 10, e4 = flat & 1023;
    float4 state = make_float4(0.f, 0.f, 0.f, 0.f);
    if (mat == 0) {
        const float* src = Akk + (size_t)bh * NC * 4096 + (size_t)e4 * 4;
        unsigned short* dst = Hkk_bf + (size_t)bh * NC * 4096 + (size_t)e4 * 4;
#pragma unroll 1
        for (int c0 = 0; c0 < NC; c0 += 4) {
            float4 av[4];
#pragma unroll
            for (int e = 0; e < 4; e++)
                av[e] = *reinterpret_cast<const float4*>(src + (size_t)(c0 + e) * 4096);
#pragma unroll
            for (int e = 0; e < 4; e++) {
                u16x4 o;
                o.x = f2bf(state.x); o.y = f2bf(state.y); o.z = f2bf(state.z); o.w = f2bf(state.w);
                *reinterpret_cast<u16x4*>(dst + (size_t)(c0 + e) * 4096) = o;
                float d = sDec[c0 + e];
                state.x = d * state.x + av[e].x;
                state.y = d * state.y + av[e].y;
                state.z = d * state.z + av[e].z;
                state.w = d * state.w + av[e].w;
            }
        }
    } else {
        float* base = HkvT + (size_t)bh * NC * 4096 + (size_t)e4 * 4;
#pragma unroll 1
        for (int c0 = 0; c0 < NC; c0 += 4) {
            float4 av[4];
#pragma unroll
            for (int e = 0; e < 4; e++)
                av[e] = *reinterpret_cast<const float4*>(base + (size_t)(c0 + e) * 4096);
#pragma unroll
            for (int e = 0; e < 4; e++) {
                *reinterpret_cast<float4*>(base + (size_t)(c0 + e) * 4096) = state;
                float d = sDec[c0 + e];
                state.x = d * state.x + av[e].x;
                state.y = d * state.y + av[e].y;
                state.z = d * state.z + av[e].z;
                state.w = d * state.w + av[e].w;
            }
        }
    }
}

// ---------------------------------------------------------------------------
// MFMA scan: ONE WAVE per (bh, chunk, half16) -> 2048 waves, 512 blocks.
// All 16-lane reductions via DPP (wsum16) -- no DS-latency chains.
// ---------------------------------------------------------------------------
__global__ __launch_bounds__(256, 2) void scan_mfma(
    const float* __restrict__ qbuf, const float* __restrict__ kbuf,
    const float* __restrict__ vbuf, const float* __restrict__ G,
    const float* __restrict__ betaT, const unsigned short* __restrict__ Hkk_bf,
    const float* __restrict__ HkvT0, const float* __restrict__ lambda_p,
    const float* __restrict__ norm_w, unsigned short* __restrict__ obf)
{
    __shared__ __align__(16) unsigned short sP[4][16][72];
    __shared__ __align__(16) unsigned short sM[4][16][40];

    const int tid = threadIdx.x;
    const int wv = tid >> 6, lane = tid & 63;
    const int quad = lane >> 4, l16 = lane & 15;
    const int W = blockIdx.x * 4 + wv;          // 0..2047
    const int half = W & 1;
    const int cidx = W >> 1;                    // 0..1023
    const int bh = cidx >> 5, chunk = cidx & 31;
    const int b = bh >> 4, h = bh & 15;
    const int t0 = chunk * CC;
    const int rbofs = 16 * half + 4 * quad;     // +reg -> local t-row
    unsigned short (*sPw)[72] = sP[wv];
    unsigned short (*sMw)[40] = sM[wv];

    const size_t rbase = ((size_t)(b * T_LEN + t0) * NH + h) * 64;
    const float* Gb = G + (size_t)bh * T_LEN + t0;
    const float* Bb = betaT + (size_t)bh * T_LEN + t0;
    const float Gprev = (chunk > 0) ? Gb[-1] : 0.f;

    float Gt[4], et[4];
#pragma unroll
    for (int reg = 0; reg < 4; reg++) {
        float g = Gb[rbofs + reg];
        Gt[reg] = g;
        et[reg] = expf(g - Gprev);
    }
    float Co[2][4];
#pragma unroll
    for (int sn = 0; sn < 2; sn++) {
        int s = 16 * sn + l16;
        float Gs = Gb[s], bts = Bb[s];
#pragma unroll
        for (int reg = 0; reg < 4; reg++) {
            int t = rbofs + reg;
            Co[sn][reg] = (s <= t) ? expf(Gt[reg] - Gs) * bts : 0.f;
        }
    }
    float lam[4], nw[4];
#pragma unroll
    for (int f = 0; f < 4; f++) {
        lam[f] = softplusf(lambda_p[h * 64 + 16 * f + l16]) + 0.25f;
        nw[f]  = norm_w[16 * f + l16];
    }

    bf16x8 Kb[2][2];
#pragma unroll
    for (int sn = 0; sn < 2; sn++) {
        const float* kr = kbuf + rbase + (size_t)(16 * sn + l16) * 1024;
#pragma unroll
        for (int ks = 0; ks < 2; ks++) {
            float4 a = *reinterpret_cast<const float4*>(kr + 8 * quad + 32 * ks);
            float4 c = *reinterpret_cast<const float4*>(kr + 8 * quad + 32 * ks + 4);
            Kb[sn][ks] = pack8(a, c);
        }
    }
    bf16x8 KTb[4];
#pragma unroll
    for (int f = 0; f < 4; f++) {
        union { bf16x8 v; unsigned short u[8]; } r;
#pragma unroll
        for (int j = 0; j < 8; j++)
            r.u[j] = f2bf(kbuf[rbase + (size_t)(8 * quad + j) * 1024 + 16 * f + l16]);
        KTb[f] = r.v;
    }
    const size_t hbase = ((size_t)(bh * NC) + chunk) * 4096;
    bf16x8 Hb[4][2];
#pragma unroll
    for (int f = 0; f < 4; f++) {
        const unsigned short* hr = Hkk_bf + hbase + (size_t)(16 * f + l16) * 64;
#pragma unroll
        for (int ks = 0; ks < 2; ks++)
            Hb[f][ks] = *reinterpret_cast<const bf16x8*>(hr + 8 * quad + 32 * ks);
    }

    f32x4 X[4], R[4], P[4];
    float rs8[4];
#pragma unroll
    for (int reg = 0; reg < 4; reg++) rs8[reg] = 0.f;
#pragma unroll
    for (int f = 0; f < 4; f++) {
#pragma unroll
        for (int reg = 0; reg < 4; reg++) {
            float q = qbuf[rbase + (size_t)(rbofs + reg) * 1024 + 16 * f + l16];
            P[f][reg] = q; R[f][reg] = q; X[f][reg] = 0.f;
            rs8[reg] += q * q;
        }
    }
#pragma unroll
    for (int reg = 0; reg < 4; reg++) rs8[reg] = wsum16(rs8[reg]);

    const f32x4 zero4 = {0.f, 0.f, 0.f, 0.f};

#pragma unroll 1
    for (int it = 0; it < CG_IT; it++) {
#pragma unroll
        for (int reg = 0; reg < 4; reg++)
#pragma unroll
            for (int f = 0; f < 4; f++)
                sPw[4 * quad + reg][16 * f + l16] = f2bf(P[f][reg]);
        __threadfence_block();
        bf16x8 Pa[2];
#pragma unroll
        for (int ks = 0; ks < 2; ks++)
            Pa[ks] = *reinterpret_cast<const bf16x8*>(&sPw[l16][8 * quad + 32 * ks]);
        f32x4 D[2];
#pragma unroll
        for (int sn = 0; sn < 2; sn++) {
            f32x4 d = __builtin_amdgcn_mfma_f32_16x16x32_bf16(Pa[0], Kb[sn][0], zero4, 0, 0, 0);
            D[sn] = __builtin_amdgcn_mfma_f32_16x16x32_bf16(Pa[1], Kb[sn][1], d, 0, 0, 0);
        }
#pragma unroll
        for (int sn = 0; sn < 2; sn++)
#pragma unroll
            for (int reg = 0; reg < 4; reg++)
                sMw[4 * quad + reg][16 * sn + l16] = f2bf(Co[sn][reg] * D[sn][reg]);
        __threadfence_block();
        bf16x8 Ma = *reinterpret_cast<const bf16x8*>(&sMw[l16][8 * quad]);
        f32x4 AP[4], A2[4];
#pragma unroll
        for (int f = 0; f < 4; f++) {
            AP[f] = __builtin_amdgcn_mfma_f32_16x16x32_bf16(Ma, KTb[f], zero4, 0, 0, 0);
            f32x4 a = __builtin_amdgcn_mfma_f32_16x16x32_bf16(Pa[0], Hb[f][0], zero4, 0, 0, 0);
            A2[f] = __builtin_amdgcn_mfma_f32_16x16x32_bf16(Pa[1], Hb[f][1], a, 0, 0, 0);
        }
#pragma unroll
        for (int f = 0; f < 4; f++)
#pragma unroll
            for (int reg = 0; reg < 4; reg++)
                AP[f][reg] = lam[f] * P[f][reg] + AP[f][reg] + et[reg] * A2[f][reg];
        float alpha[4], rsn[4];
#pragma unroll
        for (int reg = 0; reg < 4; reg++) {
            float s = 0.f;
#pragma unroll
            for (int f = 0; f < 4; f++) s += P[f][reg] * AP[f][reg];
            s = wsum16(s);
            alpha[reg] = rs8[reg] / (s + 1e-12f);
            rsn[reg] = 0.f;
        }
#pragma unroll
        for (int f = 0; f < 4; f++)
#pragma unroll
            for (int reg = 0; reg < 4; reg++) {
                X[f][reg] += alpha[reg] * P[f][reg];
                float rv = R[f][reg] - alpha[reg] * AP[f][reg];
                R[f][reg] = rv;
                rsn[reg] += rv * rv;
            }
#pragma unroll
        for (int reg = 0; reg < 4; reg++) {
            float v = wsum16(rsn[reg]);
            float btac = v / (rs8[reg] + 1e-12f);
            rs8[reg] = v;
#pragma unroll
            for (int f = 0; f < 4; f++)
                P[f][reg] = R[f][reg] + btac * P[f][reg];
        }
    }

    // ---- output phase ----
#pragma unroll
    for (int reg = 0; reg < 4; reg++)
#pragma unroll
        for (int f = 0; f < 4; f++)
            sPw[4 * quad + reg][16 * f + l16] = f2bf(X[f][reg]);
    __threadfence_block();
    bf16x8 Xa[2];
#pragma unroll
    for (int ks = 0; ks < 2; ks++)
        Xa[ks] = *reinterpret_cast<const bf16x8*>(&sPw[l16][8 * quad + 32 * ks]);
    f32x4 Do[2];
#pragma unroll
    for (int sn = 0; sn < 2; sn++) {
        f32x4 d = __builtin_amdgcn_mfma_f32_16x16x32_bf16(Xa[0], Kb[sn][0], zero4, 0, 0, 0);
        Do[sn] = __builtin_amdgcn_mfma_f32_16x16x32_bf16(Xa[1], Kb[sn][1], d, 0, 0, 0);
    }
#pragma unroll
    for (int sn = 0; sn < 2; sn++)
#pragma unroll
        for (int reg = 0; reg < 4; reg++)
            sMw[4 * quad + reg][16 * sn + l16] = f2bf(Co[sn][reg] * Do[sn][reg]);
    __threadfence_block();
    bf16x8 Mo = *reinterpret_cast<const bf16x8*>(&sMw[l16][8 * quad]);
    bf16x8 Vb[4];
#pragma unroll
    for (int f = 0; f < 4; f++) {
        union { bf16x8 v; unsigned short u[8]; } r;
#pragma unroll
        for (int j = 0; j < 8; j++)
            r.u[j] = f2bf(vbuf[rbase + (size_t)(8 * quad + j) * 1024 + 16 * f + l16]);
        Vb[f] = r.v;
    }
    bf16x8 Hvb[4][2];
#pragma unroll
    for (int f = 0; f < 4; f++) {
        const float* hr = HkvT0 + hbase + (size_t)(16 * f + l16) * 64;
#pragma unroll
        for (int ks = 0; ks < 2; ks++) {
            float4 a = *reinterpret_cast<const float4*>(hr + 8 * quad + 32 * ks);
            float4 c = *reinterpret_cast<const float4*>(hr + 8 * quad + 32 * ks + 4);
            Hvb[f][ks] = pack8(a, c);
        }
    }
    f32x4 O[4];
#pragma unroll
    for (int f = 0; f < 4; f++) {
        f32x4 o1 = __builtin_amdgcn_mfma_f32_16x16x32_bf16(Mo, Vb[f], zero4, 0, 0, 0);
        f32x4 o2 = __builtin_amdgcn_mfma_f32_16x16x32_bf16(Xa[0], Hvb[f][0], zero4, 0, 0, 0);
        o2 = __builtin_amdgcn_mfma_f32_16x16x32_bf16(Xa[1], Hvb[f][1], o2, 0, 0, 0);
#pragma unroll
        for (int reg = 0; reg < 4; reg++)
            O[f][reg] = o1[reg] + et[reg] * o2[reg];
    }
#pragma unroll
    for (int reg = 0; reg < 4; reg++) {
        float s = 0.f;
#pragma unroll
        for (int f = 0; f < 4; f++) s += O[f][reg] * O[f][reg];
        s = wsum16(s);
        float scale = rsqrtf(s * (1.f / 64.f) + 1e-5f);
        size_t orow = rbase + (size_t)(rbofs + reg) * 1024;
#pragma unroll
        for (int f = 0; f < 4; f++)
            obf[orow + 16 * f + l16] = f2bf(O[f][reg] * scale * nw[f]);
    }
}

// ---------------------------------------------------------------------------
extern "C" void kernel_launch(void* const* d_in, const int* in_sizes, int n_in,
                              void* d_out, int out_size, void* d_ws, size_t ws_size,
                              hipStream_t stream)
{
    const float* hidden   = (const float*)d_in[0];
    const float* Wq       = (const float*)d_in[1];
    const float* Wk       = (const float*)d_in[2];
    const float* Wv       = (const float*)d_in[3];
    const float* Wa       = (const float*)d_in[4];
    const float* Wb       = (const float*)d_in[5];
    const float* bb       = (const float*)d_in[6];
    const float* A_log    = (const float*)d_in[7];
    const float* dt_bias  = (const float*)d_in[8];
    const float* lambda_p = (const float*)d_in[9];
    const float* Wconv_q  = (const float*)d_in[10];
    const float* Wconv_k  = (const float*)d_in[11];
    const float* norm_w   = (const float*)d_in[12];
    const float* Wo       = (const float*)d_in[13];
    float* out = (float*)d_out;

    float* ws = (float*)d_ws;
    const size_t SZ_BIG = (size_t)2 * T_LEN * HIDN;   // 2M floats (8 MB)
    float* qpre = ws;
    float* kpre = qpre + SZ_BIG;
    float* vbuf = kpre + SZ_BIG;
    float* qbuf = vbuf + SZ_BIG;
    float* kbuf = qbuf + SZ_BIG;
    float* gbuf = kbuf + SZ_BIG;
    float* bbuf = gbuf + 32768;
    float* Gbuf = bbuf + 32768;
    float* btT  = Gbuf + 32768;
    float* Akk  = btT + 32768;                        // 4M floats (16 MB)
    float* AkvT = Akk + (size_t)32 * NC * 4096;       // 4M floats -> HkvT in-place
    unsigned short* WoT = (unsigned short*)(AkvT + (size_t)32 * NC * 4096);

    unsigned short* hidden_bf = (unsigned short*)AkvT;    // dead before chunk_local
    unsigned short* WqkvT = (unsigned short*)Akk;         // dead before chunk_local
    unsigned short* obuf_bf = (unsigned short*)kpre;      // kpre dead after conv
    unsigned short* Hkk_bf = (unsigned short*)qpre;       // qpre dead after conv (8 MB exact fit)

    const int M = 2 * T_LEN;                          // 2048

    prep<<<3072, 256, 0, stream>>>(hidden, Wq, Wk, Wv, Wo, hidden_bf, WqkvT, WoT);
    proj_gb<<<M / 4, 256, 0, stream>>>(hidden, Wa, Wb, bb, A_log, dt_bias, gbuf, bbuf);

    dim3 gq(3 * HIDN / 128, M / 128);                 // (24, 16)
    gemm_qkv128<<<gq, 256, 0, stream>>>(hidden_bf, WqkvT, qpre);
    cumsum_g<<<32, 256, 0, stream>>>(gbuf, bbuf, Gbuf, btT);
    conv_silu_l2<<<2 * M * NH / 4, 256, 0, stream>>>(qpre, kpre, Wconv_q, Wconv_k,
                                                     qbuf, kbuf);
    chunk_local<<<1024, 256, 0, stream>>>(kbuf, vbuf, Gbuf, btT, Akk, AkvT);
    chunk_prefix<<<256, 256, 0, stream>>>(Akk, AkvT, Gbuf, Hkk_bf);
    scan_mfma<<<512, 256, 0, stream>>>(qbuf, kbuf, vbuf, Gbuf, btT, Hkk_bf, AkvT,
                                       lambda_p, norm_w, obuf_bf);
    dim3 gg(HIDN / 64, M / 64);
    gemm_bf16<<<gg, 256, 0, stream>>>(obuf_bf, WoT, out, M, HIDN, HIDN);
}